// Round 11
// baseline (495.504 us; speedup 1.0000x reference)
//
#include <hip/hip_runtime.h>
#include <cstdint>

#define N_NODES 100000
#define N_EDGES 500000
#define N_GRAPHS 128
#define HID 128
#define SCAN1_B ((2 * N_NODES + 255) / 256)   // 782 blocks over concatenated counts
#define BOTH_GRID ((2 * N_EDGES + 255) / 256) // 3907 blocks over concatenated edges
#define NPART 8                               // XCD count: hist partitions
#define Z8_B ((NPART * 2 * N_NODES) / 256)    // 6250 blocks to zero cnt8

typedef __attribute__((ext_vector_type(8))) short short8;
typedef __attribute__((ext_vector_type(4))) float f32x4;

// ---- monotone float<->uint encoding for max; enc==0 marks "never written" ----
__device__ __forceinline__ unsigned encf(float f) {
    unsigned u = __float_as_uint(f);
    return (u & 0x80000000u) ? ~u : (u | 0x80000000u);
}
__device__ __forceinline__ float decf(unsigned e) {
    unsigned u = (e & 0x80000000u) ? (e & 0x7FFFFFFFu) : ~e;
    return __uint_as_float(u);
}
__device__ __forceinline__ unsigned pk_bf16(float a, float b) {
    unsigned ua = __float_as_uint(a);
    unsigned ub = __float_as_uint(b);
    ua = (ua + 0x7fffu + ((ua >> 16) & 1u)) >> 16;
    ub = (ub + 0x7fffu + ((ub >> 16) & 1u)) & 0xffff0000u;
    return ua | ub;
}
__device__ __forceinline__ ushort bf16r(float f) {
    unsigned u = __float_as_uint(f);
    return (ushort)((u + 0x7fffu + ((u >> 16) & 1u)) >> 16);
}
__device__ __forceinline__ float bf2f(ushort h) {
    return __uint_as_float((unsigned)h << 16);
}

// ---- transpose+convert weights -> bf16 [n][k]; block 384 computes wkey/bias0
//      ONCE; blocks >=385 zero cnt8 + pooled (cnt itself is fully overwritten
//      by scan1, no zeroing needed) ----
__global__ __launch_bounds__(256) void transp_prep_kernel(const float* __restrict__ W1b,
                                                          const float* __restrict__ W2b,
                                                          const float* __restrict__ W1a,
                                                          const float* __restrict__ W2a,
                                                          const float* __restrict__ W_enc,
                                                          const float* __restrict__ b_enc,
                                                          const float* __restrict__ W0,
                                                          const float* __restrict__ b0,
                                                          ushort* __restrict__ WT,
                                                          float* __restrict__ wkey,
                                                          float* __restrict__ bias0,
                                                          int* __restrict__ cnt8,
                                                          float* __restrict__ pooled) {
    int blk = blockIdx.x;
    int tid = threadIdx.x;
    if (blk >= 385) {   // zeroing duty: 6250 blocks for cnt8, 256 for pooled
        int z = blk - 385;
        if (z < Z8_B) {
            cnt8[z * 256 + tid] = 0;
        } else {
            int i = (z - Z8_B) * 256 + tid;   // exactly 128*512 = 65536 floats
            pooled[i] = 0.f;
        }
        return;
    }
    if (blk == 384) {   // prep
        if (tid < HID) {
            float wk = 0.f, bk = b0[tid];
            for (int k = 0; k < 32; ++k) {
                float w = W0[(15 + k) * HID + tid];
                wk += W_enc[k] * w;
                bk += b_enc[k] * w;
            }
            wkey[tid] = wk;
            bias0[tid] = bk;
        }
        return;
    }
    int m = blk >> 6;
    int i = (blk & 63) * 256 + tid;   // i = n*128 + k
    int n = i >> 7, k = i & 127;
    int src = k * HID + n;
    float v;
    switch (m) {
        case 0: v = W1b[src]; break;
        case 1: v = W2b[src]; break;
        case 2: v = W1a[src]; break;
        case 3: v = W1a[HID * HID + src] - W1a[src]; break;
        case 4: v = W2a[src]; break;
        default: v = W2a[HID * HID + src] - W2a[src]; break;
    }
    WT[m * HID * HID + i] = bf16r(v);
}

// ---- fused encoder + XCD-partitioned histogram. Device atomics to a shared
//      800KB cnt array migrate each 64B line across all 8 XCD L2s (~80
//      RMW/line from random XCDs) — the R10 96us cost. Partitioning by
//      part = blk&7 (dispatch round-robins blocks over XCDs) keeps each
//      copy's lines XCD-local. seq = partition-local rank; any per-part
//      assignment is a valid within-bucket bijection -> output unchanged. ----
__global__ __launch_bounds__(256) void encode_hist_kernel(const float* __restrict__ x,
                                                          const float* __restrict__ W0,
                                                          const float* __restrict__ wkey,
                                                          const float* __restrict__ bias0,
                                                          ushort* __restrict__ h,
                                                          float* __restrict__ xkey,
                                                          const int* __restrict__ dst1,
                                                          const int* __restrict__ dst2,
                                                          int* __restrict__ cnt8,
                                                          int* __restrict__ seq) {
    int blk = blockIdx.x;
    int tid = threadIdx.x;
    if (blk < BOTH_GRID) {   // hist + seq for both layers, partitioned
        int e = blk * 256 + tid;
        int part = blk & (NPART - 1);
        int* cp = cnt8 + part * (2 * N_NODES);
        if (e < N_EDGES) seq[e] = atomicAdd(&cp[dst1[e]], 1);
        else if (e < 2 * N_EDGES) seq[e] = atomicAdd(&cp[N_NODES + dst2[e - N_EDGES]], 1);
        return;
    }
    int nb = blk - BOTH_GRID;
    int n = nb * 2 + (tid >> 7);
    int j = tid & 127;
    const float* xr = x + n * 16;
    float k0 = xr[0];
    if (j == 0) xkey[n] = k0;
    float acc = bias0[j] + k0 * wkey[j];
#pragma unroll
    for (int f = 0; f < 15; ++f)
        acc = fmaf(xr[1 + f], W0[f * HID + j], acc);
    h[n * HID + j] = bf16r(fmaxf(acc, 0.f));
}

// ---- dual MFMA (N x 128 bf16) @ (128 x 128) -> bf16, LDS-restaged epilogue ----
__global__ __launch_bounds__(512, 4) void mm_mfma_dual_kernel(const ushort* __restrict__ in,
                                                              const unsigned* __restrict__ aggin,
                                                              const int* __restrict__ cntin,
                                                              const float* __restrict__ baddin,
                                                              ushort* __restrict__ xout,
                                                              const ushort* __restrict__ WuT,
                                                              const ushort* __restrict__ WvT,
                                                              const float* __restrict__ bv,
                                                              ushort* __restrict__ outu,
                                                              ushort* __restrict__ outv, int nrows) {
    __shared__ ushort sH[128 * 136];    // A-tile, then reused for D-restage
    __shared__ ushort sWT[128 * 136];   // Wu, then Wv
    int tid = threadIdx.x;
    int n0 = blockIdx.x * 128;
#pragma unroll
    for (int q = 0; q < 4; ++q) {
        int c = q * 512 + tid;
        int r = c >> 4, off = (c & 15) << 3;
        int n = n0 + r;
        uint4 vv = make_uint4(0, 0, 0, 0);
        if (n < nrows) {
            uint4 hv = *(const uint4*)(in + (size_t)n * HID + off);
            if (aggin) {
                float add[8];
#pragma unroll
                for (int p = 0; p < 8; ++p) add[p] = 0.f;
                if (cntin[n] > 0) {
                    uint4 e0 = *(const uint4*)(aggin + (size_t)n * HID + off);
                    uint4 e1 = *(const uint4*)(aggin + (size_t)n * HID + off + 4);
                    float4 bb0 = *(const float4*)(baddin + off);
                    float4 bb1 = *(const float4*)(baddin + off + 4);
                    add[0] = decf(e0.x) + bb0.x; add[1] = decf(e0.y) + bb0.y;
                    add[2] = decf(e0.z) + bb0.z; add[3] = decf(e0.w) + bb0.w;
                    add[4] = decf(e1.x) + bb1.x; add[5] = decf(e1.y) + bb1.y;
                    add[6] = decf(e1.z) + bb1.z; add[7] = decf(e1.w) + bb1.w;
                }
                unsigned hw[4] = {hv.x, hv.y, hv.z, hv.w};
                unsigned ow[4];
#pragma unroll
                for (int p = 0; p < 4; ++p) {
                    float lo = __uint_as_float(hw[p] << 16);
                    float hi = __uint_as_float(hw[p] & 0xffff0000u);
                    float r0 = fmaxf(add[2 * p] + lo, 0.f);
                    float r1 = fmaxf(add[2 * p + 1] + hi, 0.f);
                    ow[p] = pk_bf16(r0, r1);
                }
                vv = make_uint4(ow[0], ow[1], ow[2], ow[3]);
                *(uint4*)(xout + (size_t)n * HID + off) = vv;
            } else {
                vv = hv;
            }
        }
        *(uint4*)(sH + r * 136 + off) = vv;
    }
    // stage Wu
#pragma unroll
    for (int q = 0; q < 4; ++q) {
        int c = q * 512 + tid;
        int nn = c >> 4, off = (c & 15) << 3;
        *(uint4*)(sWT + nn * 136 + off) = *(const uint4*)(WuT + nn * 128 + off);
    }
    __syncthreads();

    int lane = tid & 63, wv = tid >> 6;
    int l15 = lane & 15, quad = lane >> 4;
    int ch = wv & 1, rh = wv >> 1;

    short8 afr[2][4];
#pragma unroll
    for (int rr = 0; rr < 2; ++rr) {
        const ushort* ab = sH + (rh * 32 + rr * 16 + l15) * 136 + quad * 8;
#pragma unroll
        for (int kc = 0; kc < 4; ++kc)
            afr[rr][kc] = *(const short8*)(ab + kc * 32);
    }

#pragma unroll
    for (int pass = 0; pass < 2; ++pass) {
        ushort* out = pass ? outv : outu;
        f32x4 acc[2][4];
#pragma unroll
        for (int rr = 0; rr < 2; ++rr)
#pragma unroll
            for (int ct = 0; ct < 4; ++ct) acc[rr][ct] = (f32x4){0.f, 0.f, 0.f, 0.f};
#pragma unroll
        for (int kc = 0; kc < 4; ++kc) {
#pragma unroll
            for (int ct = 0; ct < 4; ++ct) {
                short8 bfr = *(const short8*)(sWT + ((ch * 4 + ct) * 16 + l15) * 136 + quad * 8 + kc * 32);
                acc[0][ct] = __builtin_amdgcn_mfma_f32_16x16x32_bf16(afr[0][kc], bfr, acc[0][ct], 0, 0, 0);
                acc[1][ct] = __builtin_amdgcn_mfma_f32_16x16x32_bf16(afr[1][kc], bfr, acc[1][ct], 0, 0, 0);
            }
        }
        __syncthreads();   // sWT + sH(afr) reads done
#pragma unroll
        for (int ct = 0; ct < 4; ++ct) {
            int col = (ch * 4 + ct) * 16 + l15;
            float bb = pass ? bv[col] : 0.f;
#pragma unroll
            for (int rr = 0; rr < 2; ++rr) {
                int rowb = rh * 32 + rr * 16 + quad * 4;
#pragma unroll
                for (int reg = 0; reg < 4; ++reg)
                    sH[(rowb + reg) * 136 + col] = bf16r(acc[rr][ct][reg] + bb);
            }
        }
        if (pass == 0) {   // restage Wv over sWT (reads drained by the barrier above)
#pragma unroll
            for (int q = 0; q < 4; ++q) {
                int c = q * 512 + tid;
                int nn = c >> 4, off = (c & 15) << 3;
                *(uint4*)(sWT + nn * 136 + off) = *(const uint4*)(WvT + nn * 128 + off);
            }
        }
        __syncthreads();
#pragma unroll
        for (int q = 0; q < 4; ++q) {
            int c = q * 512 + tid;
            int r = c >> 4, off = (c & 15) << 3;
            int m = n0 + r;
            if (m < nrows)
                *(uint4*)(out + (size_t)m * HID + off) = *(const uint4*)(sH + r * 136 + off);
        }
    }
}

// ---- scan over per-node totals; emits cnt (totals, for mm2/pool), partBase
//      (bucket-local base + within-bucket part prefix, so build needs only ONE
//      random load per edge), and per-block partials ----
__global__ __launch_bounds__(256) void scan1_kernel(const int* __restrict__ cnt8,
                                                    int* __restrict__ cnt,
                                                    int* __restrict__ partBase,
                                                    int* __restrict__ partials) {
    __shared__ int tmp[256];
    int tid = threadIdx.x;
    int gid = blockIdx.x * 256 + tid;
    int c8[NPART];
    int t = 0;
    if (gid < 2 * N_NODES) {
#pragma unroll
        for (int p = 0; p < NPART; ++p) {
            c8[p] = cnt8[p * (2 * N_NODES) + gid];
            t += c8[p];
        }
    }
    tmp[tid] = t;
    __syncthreads();
#pragma unroll
    for (int off = 1; off < 256; off <<= 1) {
        int v = (tid >= off) ? tmp[tid - off] : 0;
        __syncthreads();
        tmp[tid] += v;
        __syncthreads();
    }
    if (gid < 2 * N_NODES) {
        int base = tmp[tid] - t;   // local exclusive
        cnt[gid] = t;
        int run = base;
#pragma unroll
        for (int p = 0; p < NPART; ++p) {
            partBase[p * (2 * N_NODES) + gid] = run;
            run += c8[p];
        }
    }
    if (tid == 255) partials[blockIdx.x] = tmp[255];
}

__global__ __launch_bounds__(1024) void scan2_kernel(int* __restrict__ partials) {
    __shared__ int tmp[1024];
    int tid = threadIdx.x;
    int v = (tid < SCAN1_B) ? partials[tid] : 0;
    tmp[tid] = v;
    __syncthreads();
#pragma unroll
    for (int off = 1; off < 1024; off <<= 1) {
        int t = (tid >= off) ? tmp[tid - off] : 0;
        __syncthreads();
        tmp[tid] += t;
        __syncthreads();
    }
    if (tid < SCAN1_B) partials[tid] = tmp[tid] - v;  // exclusive
}

// ---- fused CSR finalize (atomic-free). Part A (thread/node): expand sorted
//      dst + zero boundary agg rows. Part B (thread/edge): scatter src via
//      pos = partBase[part][dst] + partials + seq[e], part = (e>>8)&7. ----
__global__ __launch_bounds__(256) void build_kernel(const int* __restrict__ src1,
                                                    const int* __restrict__ dst1,
                                                    const int* __restrict__ src2,
                                                    const int* __restrict__ dst2,
                                                    const int* __restrict__ cnt,
                                                    const int* __restrict__ partBase,
                                                    const int* __restrict__ partials,
                                                    const int* __restrict__ seq,
                                                    int* __restrict__ srcS,
                                                    int* __restrict__ dstS,
                                                    unsigned* __restrict__ agg1,
                                                    unsigned* __restrict__ agg2) {
    int blk = blockIdx.x;
    int tid = threadIdx.x;
    if (blk < SCAN1_B) {   // part A: expand dst + zero boundary rows
        int gid = blk * 256 + tid;
        if (gid >= 2 * N_NODES) return;
        int c = cnt[gid];
        if (c == 0) return;
        int o = partBase[gid] + partials[gid >> 8];   // p=0 slot == bucket base
        int layer = gid >= N_NODES;
        int d = gid - layer * N_NODES;
        for (int i = 0; i < c; ++i) dstS[o + i] = d;
        bool spans = (o >> 4) != ((o + c - 1) >> 4);
        bool tail = (o + c == N_EDGES) || (o + c == 2 * N_EDGES);
        if (spans || tail) {
            unsigned* agg = layer ? agg2 : agg1;
            uint4* ap = (uint4*)(agg + (size_t)d * HID);
#pragma unroll
            for (int i = 0; i < 32; ++i) ap[i] = make_uint4(0u, 0u, 0u, 0u);
        }
        return;
    }
    int e = (blk - SCAN1_B) * 256 + tid;
    int s, idx;
    if (e < N_EDGES) { s = src1[e]; idx = dst1[e]; }
    else if (e < 2 * N_EDGES) { s = src2[e - N_EDGES]; idx = N_NODES + dst2[e - N_EDGES]; }
    else return;
    int part = (e >> 8) & (NPART - 1);
    int pos = partBase[part * (2 * N_NODES) + idx] + partials[idx >> 8] + seq[e];
    srcS[pos] = s;
}

// ---- edge conv: bf16 MFMA, 64-edge dst-sorted windows, 512 threads ----
__global__ __launch_bounds__(512, 6) void edge_kernel(const ushort* __restrict__ u,
                                                      const ushort* __restrict__ v,
                                                      const float* __restrict__ xkey,
                                                      const int* __restrict__ srcS,
                                                      const int* __restrict__ dstS,
                                                      const ushort* __restrict__ WbT,
                                                      const float* __restrict__ wlast,
                                                      unsigned* __restrict__ agg) {
    __shared__ ushort sWT[128 * 136];   // 34816 B: WbT[n][k] bf16, padded stride
    __shared__ ushort sU[64 * 136];     // 17408 B union: t[64][136] then msgT[128][66]
    __shared__ int sDst[64];
    __shared__ int sBnd[2];             // [0]=dst before window, [1]=dst after window
    __shared__ unsigned sMask[3];       // head-flag mask lo/hi + head64 flag
    int tid = threadIdx.x;
    int w0 = blockIdx.x * 64;

    // W stage: 2048 uint4 over 512 threads = 4 each (L2-hot 32KB)
#pragma unroll
    for (int q = 0; q < 4; ++q) {
        int c = q * 512 + tid;
        int n = c >> 4, off = (c & 15) << 3;
        *(uint4*)(sWT + n * 136 + off) = *(const uint4*)(WbT + n * 128 + off);
    }

    int eloc = tid >> 3;
    int sub = tid & 7;
    int kb = sub << 4;
    int lane = tid & 63, wv = tid >> 6;
    int l15 = lane & 15, quad = lane >> 4;
    int ch = wv & 1, rh = wv >> 1;

    // loop-invariant wlast slice for this thread's 16 columns -> registers
    float wreg[16];
    {
        const float4* wr4 = (const float4*)(wlast + kb);
#pragma unroll
        for (int q = 0; q < 4; ++q) {
            float4 wq = wr4[q];
            wreg[q * 4 + 0] = wq.x; wreg[q * 4 + 1] = wq.y;
            wreg[q * 4 + 2] = wq.z; wreg[q * 4 + 3] = wq.w;
        }
    }

    // phase 1: per-thread meta + gather + compute t
    {
        int e = w0 + eloc;
        if (e >= N_EDGES) e = N_EDGES - 1;   // clamp: idempotent under max
        int sx = srcS[e], sy = dstS[e];
        if (sub == 0) sDst[eloc] = sy;
        if (tid < 2) {
            int eb = (tid == 0) ? (w0 - 1) : (w0 + 64);
            sBnd[tid] = (eb >= 0 && eb < N_EDGES) ? dstS[eb] : -1;
        }
        float kd = xkey[sx] - xkey[sy];
        const uint4* ur = (const uint4*)(u + (size_t)sx * HID + kb);
        const uint4* vr = (const uint4*)(v + (size_t)sy * HID + kb);
        uint4 uu[2], vvv[2];
        uu[0] = ur[0]; uu[1] = ur[1];
        vvv[0] = vr[0]; vvv[1] = vr[1];
#pragma unroll
        for (int q = 0; q < 2; ++q) {
            unsigned pu[4] = {uu[q].x, uu[q].y, uu[q].z, uu[q].w};
            unsigned pv[4] = {vvv[q].x, vvv[q].y, vvv[q].z, vvv[q].w};
            unsigned pk[4];
#pragma unroll
            for (int p = 0; p < 4; ++p) {
                float a0 = __uint_as_float(pu[p] << 16) + __uint_as_float(pv[p] << 16);
                float a1 = __uint_as_float(pu[p] & 0xffff0000u) + __uint_as_float(pv[p] & 0xffff0000u);
                a0 = fmaf(kd, wreg[q * 8 + 2 * p], a0);
                a1 = fmaf(kd, wreg[q * 8 + 2 * p + 1], a1);
                a0 = fmaxf(a0, 0.1f * a0);   // leaky relu
                a1 = fmaxf(a1, 0.1f * a1);
                pk[p] = pk_bf16(a0, a1);
            }
            uint4 o; o.x = pk[0]; o.y = pk[1]; o.z = pk[2]; o.w = pk[3];
            *(uint4*)(sU + eloc * 136 + kb + q * 8) = o;
        }
    }
    __syncthreads();   // W-stage + t + sDst + sBnd ready

    // segment head flags: computed ONCE by wave 0 (uniform across columns)
    if (tid < 64) {
        int dprev = (tid == 0) ? sBnd[0] : sDst[tid - 1];
        unsigned long long m = __ballot(sDst[tid] != dprev);
        if (tid == 0) { sMask[0] = (unsigned)m; sMask[1] = (unsigned)(m >> 32); }
        if (tid == 63) sMask[2] = (sDst[63] != sBnd[1]) ? 1u : 0u;
    }

    // phase 2: MFMA. wave wv: rows (wv>>1)*16..+15, cols (wv&1)*64..+63
    short8 afr[4];
    {
        const ushort* ab = sU + (rh * 16 + l15) * 136 + quad * 8;
#pragma unroll
        for (int kc = 0; kc < 4; ++kc)
            afr[kc] = *(const short8*)(ab + kc * 32);
    }
    f32x4 acc[4];
#pragma unroll
    for (int ct = 0; ct < 4; ++ct) acc[ct] = (f32x4){0.f, 0.f, 0.f, 0.f};
#pragma unroll
    for (int kc = 0; kc < 4; ++kc) {
#pragma unroll
        for (int ct = 0; ct < 4; ++ct) {
            short8 bfr = *(const short8*)(sWT + ((ch * 4 + ct) * 16 + l15) * 136 + quad * 8 + kc * 32);
            acc[ct] = __builtin_amdgcn_mfma_f32_16x16x32_bf16(afr[kc], bfr, acc[ct], 0, 0, 0);
        }
    }
    __syncthreads();   // all t reads done -> sU reusable

    // epilogue: msgT[col][edge] bf16, stride 66 (odd dword stride -> conflict-free)
#pragma unroll
    for (int ct = 0; ct < 4; ++ct) {
        int col = (ch * 4 + ct) * 16 + l15;
        uint2 pr;
        pr.x = pk_bf16(acc[ct][0], acc[ct][1]);
        pr.y = pk_bf16(acc[ct][2], acc[ct][3]);
        *(uint2*)(sU + col * 66 + rh * 16 + quad * 4) = pr;
    }
    __syncthreads();

    // phase 3: mask-driven segmented max, 4 threads/col (16 edges each).
    {
        int j = tid & 127;
        int q4 = tid >> 7;            // 0..3 (wave-uniform)
        int base = q4 * 16;
        const ushort* mrow = sU + j * 66 + base;
        float vals[16];
#pragma unroll
        for (int q = 0; q < 4; ++q) {
            ushort4 mv = *(const ushort4*)(mrow + q * 4);
            vals[q * 4 + 0] = bf2f(mv.x);
            vals[q * 4 + 1] = bf2f(mv.y);
            vals[q * 4 + 2] = bf2f(mv.z);
            vals[q * 4 + 3] = bf2f(mv.w);
        }
        unsigned mlo = __builtin_amdgcn_readfirstlane(sMask[0]);
        unsigned mhi = __builtin_amdgcn_readfirstlane(sMask[1]);
        unsigned b64 = __builtin_amdgcn_readfirstlane(sMask[2]);
        unsigned long long mask = ((unsigned long long)mhi << 32) | mlo;
        unsigned slice = (unsigned)((mask >> base) & 0xFFFFull);
        unsigned nextbit = (q4 == 3) ? (b64 & 1u) : (unsigned)((mask >> (base + 16)) & 1ull);
        unsigned ext = slice | (nextbit << 16);
        bool contFrom = !(ext & 1u);
        float run = 0.f;
        bool first = true;
#pragma unroll
        for (int e3 = 0; e3 < 16; ++e3) {
            float vv2 = vals[e3];
            bool hb = (ext >> e3) & 1u;
            run = (e3 == 0 || hb) ? vv2 : fmaxf(run, vv2);
            bool end = (e3 == 15) || ((ext >> (e3 + 1)) & 1u);
            if (end) {
                int d = sDst[base + e3];
                unsigned en = encf(run);
                unsigned* ap = agg + (size_t)d * HID + j;
                bool useAtomic = (first && contFrom) || ((e3 == 15) && !nextbit);
                if (useAtomic) atomicMax(ap, en);
                else *ap = en;
                first = false;
            }
        }
    }
}

// ---- pooling with fused layer-2 combine: x2 never materialized; 16 slices/graph ----
__global__ __launch_bounds__(256) void pool_kernel(const ushort* __restrict__ x1,
                                                   const unsigned* __restrict__ agg2,
                                                   const float* __restrict__ b2b,
                                                   const int* __restrict__ cnt2,
                                                   const int* __restrict__ batch,
                                                   float* __restrict__ pooled) {
    int g = blockIdx.x >> 4, s = blockIdx.x & 15;
    int tid = threadIdx.x;
    int lo = 0, hi = N_NODES;
    while (lo < hi) { int mid = (lo + hi) >> 1; if (batch[mid] < g) lo = mid + 1; else hi = mid; }
    int start = lo;
    hi = N_NODES;
    while (lo < hi) { int mid = (lo + hi) >> 1; if (batch[mid] < g + 1) lo = mid + 1; else hi = mid; }
    int end = lo;
    int cnt = end - start;
    int b0 = start + (int)((long long)cnt * s / 16);
    int b1 = start + (int)((long long)cnt * (s + 1) / 16);
    if (b1 <= b0) return;
    int j = tid & 127;
    bool isx2 = tid >= 128;
    float bbj = isx2 ? b2b[j] : 0.f;
    float mx = -INFINITY, sm = 0.f;
    for (int n = b0; n < b1; ++n) {
        float xv = bf2f(x1[(size_t)n * HID + j]);
        float vv;
        if (isx2) {
            float a = 0.f;
            if (cnt2[n] > 0) a = decf(agg2[(size_t)n * HID + j]) + bbj;
            vv = fmaxf(a + xv, 0.f);
        } else {
            vv = xv;
        }
        mx = fmaxf(mx, vv);
        sm += vv;
    }
    atomicMax((unsigned*)pooled + (size_t)g * 512 + tid, encf(mx));
    atomicAdd(pooled + (size_t)g * 512 + 256 + tid, sm);
}

// ---- final MLP + log_softmax ----
__global__ __launch_bounds__(128) void final_kernel(const float* __restrict__ pooled,
                                                    const int* __restrict__ batch,
                                                    const float* __restrict__ Wf1,
                                                    const float* __restrict__ bf1,
                                                    const float* __restrict__ Wf2,
                                                    const float* __restrict__ bf2,
                                                    float* __restrict__ out) {
    __shared__ float sP[512];
    __shared__ float sH[128];
    int g = blockIdx.x, tid = threadIdx.x;
    int lo = 0, hi = N_NODES;
    while (lo < hi) { int mid = (lo + hi) >> 1; if (batch[mid] < g) lo = mid + 1; else hi = mid; }
    int start = lo;
    hi = N_NODES;
    while (lo < hi) { int mid = (lo + hi) >> 1; if (batch[mid] < g + 1) lo = mid + 1; else hi = mid; }
    int cnt = lo - start;
    float inv = 1.f / (float)(cnt > 1 ? cnt : 1);
#pragma unroll
    for (int q = 0; q < 4; ++q) {
        int idx = q * 128 + tid;
        float raw;
        if (idx < 256) {
            unsigned e = ((const unsigned*)pooled)[(size_t)g * 512 + idx];
            raw = (e == 0u) ? 0.f : decf(e);
        } else {
            raw = pooled[(size_t)g * 512 + idx] * inv;
        }
        sP[idx] = raw;
    }
    __syncthreads();
    float acc = bf1[tid];
    for (int k = 0; k < 512; ++k) acc = fmaf(sP[k], Wf1[k * HID + tid], acc);
    sH[tid] = fmaxf(acc, 0.f);
    __syncthreads();
    if (tid < 2) {
        float l = bf2[tid];
        for (int k = 0; k < 128; ++k) l = fmaf(sH[k], Wf2[k * 2 + tid], l);
        sP[tid] = l;
    }
    __syncthreads();
    if (tid == 0) {
        float l0 = sP[0], l1 = sP[1];
        float m = fmaxf(l0, l1);
        float ls = m + logf(expf(l0 - m) + expf(l1 - m));
        out[g * 2 + 0] = l0 - ls;
        out[g * 2 + 1] = l1 - ls;
    }
}

extern "C" void kernel_launch(void* const* d_in, const int* in_sizes, int n_in,
                              void* d_out, int out_size, void* d_ws, size_t ws_size,
                              hipStream_t stream) {
    const float* x     = (const float*)d_in[0];
    const float* W_enc = (const float*)d_in[1];
    const float* b_enc = (const float*)d_in[2];
    const float* W0    = (const float*)d_in[3];
    const float* b0    = (const float*)d_in[4];
    const float* W1a   = (const float*)d_in[5];
    const float* b1a   = (const float*)d_in[6];
    const float* W1b   = (const float*)d_in[7];
    const float* b1b   = (const float*)d_in[8];
    const float* W2a   = (const float*)d_in[9];
    const float* b2a   = (const float*)d_in[10];
    const float* W2b   = (const float*)d_in[11];
    const float* b2b   = (const float*)d_in[12];
    const float* Wf1   = (const float*)d_in[13];
    const float* bf1   = (const float*)d_in[14];
    const float* Wf2   = (const float*)d_in[15];
    const float* bf2   = (const float*)d_in[16];
    const int* src1    = (const int*)d_in[17];
    const int* dst1    = (const int*)d_in[18];
    const int* src2    = (const int*)d_in[19];
    const int* dst2    = (const int*)d_in[20];
    const int* batch   = (const int*)d_in[21];

    const size_t NB = (size_t)N_NODES * HID;     // 12.8M elements
    ushort* hbuf  = (ushort*)d_ws;               // h -> x1 (in place, bf16)
    unsigned* agg1 = (unsigned*)(hbuf + NB);     // layer-1 segment-max (u32 encoded)
    unsigned* agg2 = agg1 + NB;                  // layer-2 segment-max
    ushort* ubuf  = (ushort*)(agg2 + NB);        // u bf16
    ushort* vbuf  = ubuf + NB;                   // v bf16
    ushort* WT    = vbuf + NB;                   // 6 x 16384 bf16: Wb1,Wb2,Wu1,Wv1,Wu2,Wv2
    ushort* WbT1 = WT;
    ushort* WbT2 = WT + 1 * HID * HID;
    ushort* WuT1 = WT + 2 * HID * HID;
    ushort* WvT1 = WT + 3 * HID * HID;
    ushort* WuT2 = WT + 4 * HID * HID;
    ushort* WvT2 = WT + 5 * HID * HID;
    float* wkey  = (float*)(WT + 6 * HID * HID);
    float* bias0 = wkey + 128;
    float* xkey  = bias0 + 128;                  // dense per-node key (N_NODES fp32)
    float* pooled = xkey + N_NODES;              // 128*512 fp32
    int* cnt    = (int*)(pooled + 128 * 512);    // 2*N_NODES totals (mm2/pool consume)
    int* cnt8   = cnt + 2 * N_NODES;             // 8 x 2*N_NODES partitioned counts
    int* partBase = cnt8 + NPART * 2 * N_NODES;  // 8 x 2*N_NODES bucket+part bases
    int* partials = partBase + NPART * 2 * N_NODES;  // 1024
    int* srcS = partials + 1024;                 // 2*N_EDGES sorted src
    int* dstS = srcS + 2 * N_EDGES;              // 2*N_EDGES sorted dst (dense expand)
    int* seq  = dstS + 2 * N_EDGES;              // 2*N_EDGES within-(part,dst) sequence

    const int edgeGrid = (N_EDGES + 63) / 64;         // 7813 windows of 64
    const int mmGrid   = (N_NODES + 127) / 128;       // 782
    const int prepGrid = 385 + Z8_B + 256;            // transpose+prep+zero(cnt8,pooled)
    const int encHistGrid = BOTH_GRID + N_NODES / 2;  // hist + encode fused
    const int buildGrid = SCAN1_B + BOTH_GRID;        // expand/zbound + scatter-src

    transp_prep_kernel<<<prepGrid, 256, 0, stream>>>(W1b, W2b, W1a, W2a, W_enc, b_enc, W0, b0,
                                                     WT, wkey, bias0, cnt8, pooled);
    encode_hist_kernel<<<encHistGrid, 256, 0, stream>>>(x, W0, wkey, bias0, hbuf, xkey,
                                                        dst1, dst2, cnt8, seq);

    // ---- CSR finalize (atomic-free past hist): scan + fused expand/zbound/scatter ----
    scan1_kernel<<<SCAN1_B, 256, 0, stream>>>(cnt8, cnt, partBase, partials);
    scan2_kernel<<<1, 1024, 0, stream>>>(partials);
    build_kernel<<<buildGrid, 256, 0, stream>>>(src1, dst1, src2, dst2, cnt, partBase, partials,
                                                seq, srcS, dstS, agg1, agg2);

    // ---- layer 1 ----
    mm_mfma_dual_kernel<<<mmGrid, 512, 0, stream>>>(hbuf, nullptr, nullptr, nullptr, nullptr,
                                                    WuT1, WvT1, b1a, ubuf, vbuf, N_NODES);
    edge_kernel<<<edgeGrid, 512, 0, stream>>>(ubuf, vbuf, xkey, srcS, dstS, WbT1,
                                              W1a + 256 * HID, agg1);

    // ---- layer 2 (mm fuses layer-1 combine; writes x1 to hbuf) ----
    mm_mfma_dual_kernel<<<mmGrid, 512, 0, stream>>>(hbuf, agg1, cnt, b1b, hbuf,
                                                    WuT2, WvT2, b2a, ubuf, vbuf, N_NODES);
    edge_kernel<<<edgeGrid, 512, 0, stream>>>(ubuf, vbuf, xkey, srcS + N_EDGES, dstS + N_EDGES,
                                              WbT2, W2a + 256 * HID, agg2);

    // ---- pooling (layer-2 combine fused; pooled zeroed by transp_prep) + head ----
    pool_kernel<<<N_GRAPHS * 16, 256, 0, stream>>>(hbuf, agg2, b2b, cnt + N_NODES, batch, pooled);
    final_kernel<<<N_GRAPHS, 128, 0, stream>>>(pooled, batch, Wf1, bf1, Wf2, bf2, (float*)d_out);
}

// Round 12
// 463.281 us; speedup vs baseline: 1.0696x; 1.0696x over previous
//
#include <hip/hip_runtime.h>
#include <cstdint>

#define N_NODES 100000
#define N_EDGES 500000
#define N_GRAPHS 128
#define HID 128
#define SCAN1_B ((2 * N_NODES + 255) / 256)   // 782 blocks over concatenated counts
#define BOTH_GRID ((2 * N_EDGES + 255) / 256) // 3907 blocks over concatenated edges
#define MM_G ((N_NODES + 127) / 128)          // 782 mm blocks
#define A_G ((2 * N_NODES + 511) / 512)       // 391 expand/zbound blocks (512 thr)
#define B_G ((2 * N_EDGES + 511) / 512)       // 1954 scatter blocks (512 thr)

typedef __attribute__((ext_vector_type(8))) short short8;
typedef __attribute__((ext_vector_type(4))) float f32x4;

// ---- monotone float<->uint encoding for max; enc==0 marks "never written" ----
__device__ __forceinline__ unsigned encf(float f) {
    unsigned u = __float_as_uint(f);
    return (u & 0x80000000u) ? ~u : (u | 0x80000000u);
}
__device__ __forceinline__ float decf(unsigned e) {
    unsigned u = (e & 0x80000000u) ? (e & 0x7FFFFFFFu) : ~e;
    return __uint_as_float(u);
}
__device__ __forceinline__ unsigned pk_bf16(float a, float b) {
    unsigned ua = __float_as_uint(a);
    unsigned ub = __float_as_uint(b);
    ua = (ua + 0x7fffu + ((ua >> 16) & 1u)) >> 16;
    ub = (ub + 0x7fffu + ((ub >> 16) & 1u)) & 0xffff0000u;
    return ua | ub;
}
__device__ __forceinline__ ushort bf16r(float f) {
    unsigned u = __float_as_uint(f);
    return (ushort)((u + 0x7fffu + ((u >> 16) & 1u)) >> 16);
}
__device__ __forceinline__ float bf2f(ushort h) {
    return __uint_as_float((unsigned)h << 16);
}

// ---- D1: transpose weights + prep + zero pooled + HIST (fused).
// hist (1M random atomics, the ~90us L2-atomic-occupancy wall: R11 proved it
// is per-atomic cost, not contention) depends only on raw dst inputs, so it
// runs here while the transpose/prep hide under it. cnt zeroed by a prior
// hipMemsetAsync. seq[e] = atomicAdd return = within-bucket rank. ----
__global__ __launch_bounds__(256) void prep_hist_kernel(const float* __restrict__ W1b,
                                                        const float* __restrict__ W2b,
                                                        const float* __restrict__ W1a,
                                                        const float* __restrict__ W2a,
                                                        const float* __restrict__ W_enc,
                                                        const float* __restrict__ b_enc,
                                                        const float* __restrict__ W0,
                                                        const float* __restrict__ b0,
                                                        ushort* __restrict__ WT,
                                                        float* __restrict__ wkey,
                                                        float* __restrict__ bias0,
                                                        float* __restrict__ pooled,
                                                        const int* __restrict__ dst1,
                                                        const int* __restrict__ dst2,
                                                        int* __restrict__ cnt,
                                                        int* __restrict__ seq) {
    int blk = blockIdx.x;
    int tid = threadIdx.x;
    if (blk >= 641) {   // hist
        int e = (blk - 641) * 256 + tid;
        if (e < N_EDGES) seq[e] = atomicAdd(&cnt[dst1[e]], 1);
        else if (e < 2 * N_EDGES) seq[e] = atomicAdd(&cnt[N_NODES + dst2[e - N_EDGES]], 1);
        return;
    }
    if (blk >= 385) {   // zero pooled (exactly 256*256 = 65536 floats)
        pooled[(blk - 385) * 256 + tid] = 0.f;
        return;
    }
    if (blk == 384) {   // prep
        if (tid < HID) {
            float wk = 0.f, bk = b0[tid];
            for (int k = 0; k < 32; ++k) {
                float w = W0[(15 + k) * HID + tid];
                wk += W_enc[k] * w;
                bk += b_enc[k] * w;
            }
            wkey[tid] = wk;
            bias0[tid] = bk;
        }
        return;
    }
    int m = blk >> 6;
    int i = (blk & 63) * 256 + tid;   // i = n*128 + k
    int n = i >> 7, k = i & 127;
    int src = k * HID + n;
    float v;
    switch (m) {
        case 0: v = W1b[src]; break;
        case 1: v = W2b[src]; break;
        case 2: v = W1a[src]; break;
        case 3: v = W1a[HID * HID + src] - W1a[src]; break;
        case 4: v = W2a[src]; break;
        default: v = W2a[HID * HID + src] - W2a[src]; break;
    }
    WT[m * HID * HID + i] = bf16r(v);
}

__global__ __launch_bounds__(256) void scan1_kernel(const int* __restrict__ cnt,
                                                    int* __restrict__ cursor,
                                                    int* __restrict__ partials) {
    __shared__ int tmp[256];
    int tid = threadIdx.x;
    int gid = blockIdx.x * 256 + tid;
    int v = (gid < 2 * N_NODES) ? cnt[gid] : 0;
    tmp[tid] = v;
    __syncthreads();
#pragma unroll
    for (int off = 1; off < 256; off <<= 1) {
        int t = (tid >= off) ? tmp[tid - off] : 0;
        __syncthreads();
        tmp[tid] += t;
        __syncthreads();
    }
    if (gid < 2 * N_NODES) cursor[gid] = tmp[tid] - v;   // local exclusive
    if (tid == 255) partials[blockIdx.x] = tmp[255];
}

__global__ __launch_bounds__(1024) void scan2_kernel(int* __restrict__ partials) {
    __shared__ int tmp[1024];
    int tid = threadIdx.x;
    int v = (tid < SCAN1_B) ? partials[tid] : 0;
    tmp[tid] = v;
    __syncthreads();
#pragma unroll
    for (int off = 1; off < 1024; off <<= 1) {
        int t = (tid >= off) ? tmp[tid - off] : 0;
        __syncthreads();
        tmp[tid] += t;
        __syncthreads();
    }
    if (tid < SCAN1_B) partials[tid] = tmp[tid] - v;  // exclusive
}

// ---- D4 fused: [mm1 with INLINE ENCODE] + [CSR build] — mutually independent
// (mm needs only prep; build needs only scan) so build's scattered-store
// latency hides under mm's MFMA. Encode inlined into mm's A-stage with
// bit-identical expression order; writes hbuf + xkey on the way. ----
__global__ __launch_bounds__(512, 4) void build_mm_kernel(const float* __restrict__ x,
                                                          const float* __restrict__ W0,
                                                          const float* __restrict__ wkey,
                                                          const float* __restrict__ bias0,
                                                          ushort* __restrict__ h,
                                                          float* __restrict__ xkey,
                                                          const ushort* __restrict__ WuT,
                                                          const ushort* __restrict__ WvT,
                                                          const float* __restrict__ bv,
                                                          ushort* __restrict__ outu,
                                                          ushort* __restrict__ outv,
                                                          const int* __restrict__ src1,
                                                          const int* __restrict__ dst1,
                                                          const int* __restrict__ src2,
                                                          const int* __restrict__ dst2,
                                                          const int* __restrict__ cnt,
                                                          const int* __restrict__ cursor,
                                                          const int* __restrict__ partials,
                                                          const int* __restrict__ seq,
                                                          int* __restrict__ srcS,
                                                          int* __restrict__ dstS,
                                                          unsigned* __restrict__ agg1,
                                                          unsigned* __restrict__ agg2) {
    __shared__ ushort sH[128 * 136];    // A-tile, then reused for D-restage
    __shared__ ushort sWT[128 * 136];   // Wu, then Wv
    int blk = blockIdx.x;
    int tid = threadIdx.x;

    if (blk >= MM_G) {
        int zb = blk - MM_G;
        if (zb < A_G) {   // expand dst + zero boundary agg rows
            int gid = zb * 512 + tid;
            if (gid >= 2 * N_NODES) return;
            int c = cnt[gid];
            if (c == 0) return;
            int o = cursor[gid] + partials[gid >> 8];
            int layer = gid >= N_NODES;
            int d = gid - layer * N_NODES;
            for (int i = 0; i < c; ++i) dstS[o + i] = d;
            bool spans = (o >> 4) != ((o + c - 1) >> 4);
            bool tail = (o + c == N_EDGES) || (o + c == 2 * N_EDGES);
            if (spans || tail) {
                unsigned* agg = layer ? agg2 : agg1;
                uint4* ap = (uint4*)(agg + (size_t)d * HID);
#pragma unroll
                for (int i = 0; i < 32; ++i) ap[i] = make_uint4(0u, 0u, 0u, 0u);
            }
            return;
        }
        int e = (zb - A_G) * 512 + tid;   // scatter src (atomic-free)
        int s, idx;
        if (e < N_EDGES) { s = src1[e]; idx = dst1[e]; }
        else if (e < 2 * N_EDGES) { s = src2[e - N_EDGES]; idx = N_NODES + dst2[e - N_EDGES]; }
        else return;
        int pos = cursor[idx] + partials[idx >> 8] + seq[e];
        srcS[pos] = s;
        return;
    }

    // ---- mm1 with inline encode ----
    int n0 = blk * 128;
#pragma unroll
    for (int q = 0; q < 4; ++q) {
        int c = q * 512 + tid;
        int r = c >> 4, off = (c & 15) << 3;
        int n = n0 + r;
        uint4 vv = make_uint4(0, 0, 0, 0);
        if (n < N_NODES) {
            const float* xr = x + n * 16;
            float k0 = xr[0];
            if (off == 0) xkey[n] = k0;
            float xf[15];
#pragma unroll
            for (int f = 0; f < 15; ++f) xf[f] = xr[1 + f];
            unsigned ow[4];
#pragma unroll
            for (int p = 0; p < 4; ++p) {
                int c0 = off + 2 * p;
                float a0 = bias0[c0] + k0 * wkey[c0];
                float a1 = bias0[c0 + 1] + k0 * wkey[c0 + 1];
#pragma unroll
                for (int f = 0; f < 15; ++f) {
                    float2 w2 = *(const float2*)(W0 + f * HID + c0);
                    a0 = fmaf(xf[f], w2.x, a0);
                    a1 = fmaf(xf[f], w2.y, a1);
                }
                ow[p] = pk_bf16(fmaxf(a0, 0.f), fmaxf(a1, 0.f));
            }
            vv = make_uint4(ow[0], ow[1], ow[2], ow[3]);
            *(uint4*)(h + (size_t)n * HID + off) = vv;
        }
        *(uint4*)(sH + r * 136 + off) = vv;
    }
    // stage Wu
#pragma unroll
    for (int q = 0; q < 4; ++q) {
        int c = q * 512 + tid;
        int nn = c >> 4, off = (c & 15) << 3;
        *(uint4*)(sWT + nn * 136 + off) = *(const uint4*)(WuT + nn * 128 + off);
    }
    __syncthreads();

    int lane = tid & 63, wv = tid >> 6;
    int l15 = lane & 15, quad = lane >> 4;
    int ch = wv & 1, rh = wv >> 1;

    short8 afr[2][4];
#pragma unroll
    for (int rr = 0; rr < 2; ++rr) {
        const ushort* ab = sH + (rh * 32 + rr * 16 + l15) * 136 + quad * 8;
#pragma unroll
        for (int kc = 0; kc < 4; ++kc)
            afr[rr][kc] = *(const short8*)(ab + kc * 32);
    }

#pragma unroll
    for (int pass = 0; pass < 2; ++pass) {
        ushort* out = pass ? outv : outu;
        f32x4 acc[2][4];
#pragma unroll
        for (int rr = 0; rr < 2; ++rr)
#pragma unroll
            for (int ct = 0; ct < 4; ++ct) acc[rr][ct] = (f32x4){0.f, 0.f, 0.f, 0.f};
#pragma unroll
        for (int kc = 0; kc < 4; ++kc) {
#pragma unroll
            for (int ct = 0; ct < 4; ++ct) {
                short8 bfr = *(const short8*)(sWT + ((ch * 4 + ct) * 16 + l15) * 136 + quad * 8 + kc * 32);
                acc[0][ct] = __builtin_amdgcn_mfma_f32_16x16x32_bf16(afr[0][kc], bfr, acc[0][ct], 0, 0, 0);
                acc[1][ct] = __builtin_amdgcn_mfma_f32_16x16x32_bf16(afr[1][kc], bfr, acc[1][ct], 0, 0, 0);
            }
        }
        __syncthreads();   // sWT + sH(afr) reads done
#pragma unroll
        for (int ct = 0; ct < 4; ++ct) {
            int col = (ch * 4 + ct) * 16 + l15;
            float bb = pass ? bv[col] : 0.f;
#pragma unroll
            for (int rr = 0; rr < 2; ++rr) {
                int rowb = rh * 32 + rr * 16 + quad * 4;
#pragma unroll
                for (int reg = 0; reg < 4; ++reg)
                    sH[(rowb + reg) * 136 + col] = bf16r(acc[rr][ct][reg] + bb);
            }
        }
        if (pass == 0) {   // restage Wv over sWT (reads drained by the barrier above)
#pragma unroll
            for (int q = 0; q < 4; ++q) {
                int c = q * 512 + tid;
                int nn = c >> 4, off = (c & 15) << 3;
                *(uint4*)(sWT + nn * 136 + off) = *(const uint4*)(WvT + nn * 128 + off);
            }
        }
        __syncthreads();
#pragma unroll
        for (int q = 0; q < 4; ++q) {
            int c = q * 512 + tid;
            int r = c >> 4, off = (c & 15) << 3;
            int m = n0 + r;
            if (m < N_NODES)
                *(uint4*)(out + (size_t)m * HID + off) = *(const uint4*)(sH + r * 136 + off);
        }
    }
}

// ---- dual MFMA (used for layer 2: fused layer-1 combine) ----
__global__ __launch_bounds__(512, 4) void mm_mfma_dual_kernel(const ushort* __restrict__ in,
                                                              const unsigned* __restrict__ aggin,
                                                              const int* __restrict__ cntin,
                                                              const float* __restrict__ baddin,
                                                              ushort* __restrict__ xout,
                                                              const ushort* __restrict__ WuT,
                                                              const ushort* __restrict__ WvT,
                                                              const float* __restrict__ bv,
                                                              ushort* __restrict__ outu,
                                                              ushort* __restrict__ outv, int nrows) {
    __shared__ ushort sH[128 * 136];    // A-tile, then reused for D-restage
    __shared__ ushort sWT[128 * 136];   // Wu, then Wv
    int tid = threadIdx.x;
    int n0 = blockIdx.x * 128;
#pragma unroll
    for (int q = 0; q < 4; ++q) {
        int c = q * 512 + tid;
        int r = c >> 4, off = (c & 15) << 3;
        int n = n0 + r;
        uint4 vv = make_uint4(0, 0, 0, 0);
        if (n < nrows) {
            uint4 hv = *(const uint4*)(in + (size_t)n * HID + off);
            float add[8];
#pragma unroll
            for (int p = 0; p < 8; ++p) add[p] = 0.f;
            if (cntin[n] > 0) {
                uint4 e0 = *(const uint4*)(aggin + (size_t)n * HID + off);
                uint4 e1 = *(const uint4*)(aggin + (size_t)n * HID + off + 4);
                float4 bb0 = *(const float4*)(baddin + off);
                float4 bb1 = *(const float4*)(baddin + off + 4);
                add[0] = decf(e0.x) + bb0.x; add[1] = decf(e0.y) + bb0.y;
                add[2] = decf(e0.z) + bb0.z; add[3] = decf(e0.w) + bb0.w;
                add[4] = decf(e1.x) + bb1.x; add[5] = decf(e1.y) + bb1.y;
                add[6] = decf(e1.z) + bb1.z; add[7] = decf(e1.w) + bb1.w;
            }
            unsigned hw[4] = {hv.x, hv.y, hv.z, hv.w};
            unsigned ow[4];
#pragma unroll
            for (int p = 0; p < 4; ++p) {
                float lo = __uint_as_float(hw[p] << 16);
                float hi = __uint_as_float(hw[p] & 0xffff0000u);
                float r0 = fmaxf(add[2 * p] + lo, 0.f);
                float r1 = fmaxf(add[2 * p + 1] + hi, 0.f);
                ow[p] = pk_bf16(r0, r1);
            }
            vv = make_uint4(ow[0], ow[1], ow[2], ow[3]);
            *(uint4*)(xout + (size_t)n * HID + off) = vv;
        }
        *(uint4*)(sH + r * 136 + off) = vv;
    }
    // stage Wu
#pragma unroll
    for (int q = 0; q < 4; ++q) {
        int c = q * 512 + tid;
        int nn = c >> 4, off = (c & 15) << 3;
        *(uint4*)(sWT + nn * 136 + off) = *(const uint4*)(WuT + nn * 128 + off);
    }
    __syncthreads();

    int lane = tid & 63, wv = tid >> 6;
    int l15 = lane & 15, quad = lane >> 4;
    int ch = wv & 1, rh = wv >> 1;

    short8 afr[2][4];
#pragma unroll
    for (int rr = 0; rr < 2; ++rr) {
        const ushort* ab = sH + (rh * 32 + rr * 16 + l15) * 136 + quad * 8;
#pragma unroll
        for (int kc = 0; kc < 4; ++kc)
            afr[rr][kc] = *(const short8*)(ab + kc * 32);
    }

#pragma unroll
    for (int pass = 0; pass < 2; ++pass) {
        ushort* out = pass ? outv : outu;
        f32x4 acc[2][4];
#pragma unroll
        for (int rr = 0; rr < 2; ++rr)
#pragma unroll
            for (int ct = 0; ct < 4; ++ct) acc[rr][ct] = (f32x4){0.f, 0.f, 0.f, 0.f};
#pragma unroll
        for (int kc = 0; kc < 4; ++kc) {
#pragma unroll
            for (int ct = 0; ct < 4; ++ct) {
                short8 bfr = *(const short8*)(sWT + ((ch * 4 + ct) * 16 + l15) * 136 + quad * 8 + kc * 32);
                acc[0][ct] = __builtin_amdgcn_mfma_f32_16x16x32_bf16(afr[0][kc], bfr, acc[0][ct], 0, 0, 0);
                acc[1][ct] = __builtin_amdgcn_mfma_f32_16x16x32_bf16(afr[1][kc], bfr, acc[1][ct], 0, 0, 0);
            }
        }
        __syncthreads();   // sWT + sH(afr) reads done
#pragma unroll
        for (int ct = 0; ct < 4; ++ct) {
            int col = (ch * 4 + ct) * 16 + l15;
            float bb = pass ? bv[col] : 0.f;
#pragma unroll
            for (int rr = 0; rr < 2; ++rr) {
                int rowb = rh * 32 + rr * 16 + quad * 4;
#pragma unroll
                for (int reg = 0; reg < 4; ++reg)
                    sH[(rowb + reg) * 136 + col] = bf16r(acc[rr][ct][reg] + bb);
            }
        }
        if (pass == 0) {   // restage Wv over sWT (reads drained by the barrier above)
#pragma unroll
            for (int q = 0; q < 4; ++q) {
                int c = q * 512 + tid;
                int nn = c >> 4, off = (c & 15) << 3;
                *(uint4*)(sWT + nn * 136 + off) = *(const uint4*)(WvT + nn * 128 + off);
            }
        }
        __syncthreads();
#pragma unroll
        for (int q = 0; q < 4; ++q) {
            int c = q * 512 + tid;
            int r = c >> 4, off = (c & 15) << 3;
            int m = n0 + r;
            if (m < nrows)
                *(uint4*)(out + (size_t)m * HID + off) = *(const uint4*)(sH + r * 136 + off);
        }
    }
}

// ---- edge conv: bf16 MFMA, 64-edge dst-sorted windows, 512 threads ----
__global__ __launch_bounds__(512, 6) void edge_kernel(const ushort* __restrict__ u,
                                                      const ushort* __restrict__ v,
                                                      const float* __restrict__ xkey,
                                                      const int* __restrict__ srcS,
                                                      const int* __restrict__ dstS,
                                                      const ushort* __restrict__ WbT,
                                                      const float* __restrict__ wlast,
                                                      unsigned* __restrict__ agg) {
    __shared__ ushort sWT[128 * 136];   // 34816 B: WbT[n][k] bf16, padded stride
    __shared__ ushort sU[64 * 136];     // 17408 B union: t[64][136] then msgT[128][66]
    __shared__ int sDst[64];
    __shared__ int sBnd[2];             // [0]=dst before window, [1]=dst after window
    __shared__ unsigned sMask[3];       // head-flag mask lo/hi + head64 flag
    int tid = threadIdx.x;
    int w0 = blockIdx.x * 64;

    // W stage: 2048 uint4 over 512 threads = 4 each (L2-hot 32KB)
#pragma unroll
    for (int q = 0; q < 4; ++q) {
        int c = q * 512 + tid;
        int n = c >> 4, off = (c & 15) << 3;
        *(uint4*)(sWT + n * 136 + off) = *(const uint4*)(WbT + n * 128 + off);
    }

    int eloc = tid >> 3;
    int sub = tid & 7;
    int kb = sub << 4;
    int lane = tid & 63, wv = tid >> 6;
    int l15 = lane & 15, quad = lane >> 4;
    int ch = wv & 1, rh = wv >> 1;

    // loop-invariant wlast slice for this thread's 16 columns -> registers
    float wreg[16];
    {
        const float4* wr4 = (const float4*)(wlast + kb);
#pragma unroll
        for (int q = 0; q < 4; ++q) {
            float4 wq = wr4[q];
            wreg[q * 4 + 0] = wq.x; wreg[q * 4 + 1] = wq.y;
            wreg[q * 4 + 2] = wq.z; wreg[q * 4 + 3] = wq.w;
        }
    }

    // phase 1: per-thread meta + gather + compute t
    {
        int e = w0 + eloc;
        if (e >= N_EDGES) e = N_EDGES - 1;   // clamp: idempotent under max
        int sx = srcS[e], sy = dstS[e];
        if (sub == 0) sDst[eloc] = sy;
        if (tid < 2) {
            int eb = (tid == 0) ? (w0 - 1) : (w0 + 64);
            sBnd[tid] = (eb >= 0 && eb < N_EDGES) ? dstS[eb] : -1;
        }
        float kd = xkey[sx] - xkey[sy];
        const uint4* ur = (const uint4*)(u + (size_t)sx * HID + kb);
        const uint4* vr = (const uint4*)(v + (size_t)sy * HID + kb);
        uint4 uu[2], vvv[2];
        uu[0] = ur[0]; uu[1] = ur[1];
        vvv[0] = vr[0]; vvv[1] = vr[1];
#pragma unroll
        for (int q = 0; q < 2; ++q) {
            unsigned pu[4] = {uu[q].x, uu[q].y, uu[q].z, uu[q].w};
            unsigned pv[4] = {vvv[q].x, vvv[q].y, vvv[q].z, vvv[q].w};
            unsigned pk[4];
#pragma unroll
            for (int p = 0; p < 4; ++p) {
                float a0 = __uint_as_float(pu[p] << 16) + __uint_as_float(pv[p] << 16);
                float a1 = __uint_as_float(pu[p] & 0xffff0000u) + __uint_as_float(pv[p] & 0xffff0000u);
                a0 = fmaf(kd, wreg[q * 8 + 2 * p], a0);
                a1 = fmaf(kd, wreg[q * 8 + 2 * p + 1], a1);
                a0 = fmaxf(a0, 0.1f * a0);   // leaky relu
                a1 = fmaxf(a1, 0.1f * a1);
                pk[p] = pk_bf16(a0, a1);
            }
            uint4 o; o.x = pk[0]; o.y = pk[1]; o.z = pk[2]; o.w = pk[3];
            *(uint4*)(sU + eloc * 136 + kb + q * 8) = o;
        }
    }
    __syncthreads();   // W-stage + t + sDst + sBnd ready

    // segment head flags: computed ONCE by wave 0 (uniform across columns)
    if (tid < 64) {
        int dprev = (tid == 0) ? sBnd[0] : sDst[tid - 1];
        unsigned long long m = __ballot(sDst[tid] != dprev);
        if (tid == 0) { sMask[0] = (unsigned)m; sMask[1] = (unsigned)(m >> 32); }
        if (tid == 63) sMask[2] = (sDst[63] != sBnd[1]) ? 1u : 0u;
    }

    // phase 2: MFMA. wave wv: rows (wv>>1)*16..+15, cols (wv&1)*64..+63
    short8 afr[4];
    {
        const ushort* ab = sU + (rh * 16 + l15) * 136 + quad * 8;
#pragma unroll
        for (int kc = 0; kc < 4; ++kc)
            afr[kc] = *(const short8*)(ab + kc * 32);
    }
    f32x4 acc[4];
#pragma unroll
    for (int ct = 0; ct < 4; ++ct) acc[ct] = (f32x4){0.f, 0.f, 0.f, 0.f};
#pragma unroll
    for (int kc = 0; kc < 4; ++kc) {
#pragma unroll
        for (int ct = 0; ct < 4; ++ct) {
            short8 bfr = *(const short8*)(sWT + ((ch * 4 + ct) * 16 + l15) * 136 + quad * 8 + kc * 32);
            acc[ct] = __builtin_amdgcn_mfma_f32_16x16x32_bf16(afr[kc], bfr, acc[ct], 0, 0, 0);
        }
    }
    __syncthreads();   // all t reads done -> sU reusable

    // epilogue: msgT[col][edge] bf16, stride 66 (odd dword stride -> conflict-free)
#pragma unroll
    for (int ct = 0; ct < 4; ++ct) {
        int col = (ch * 4 + ct) * 16 + l15;
        uint2 pr;
        pr.x = pk_bf16(acc[ct][0], acc[ct][1]);
        pr.y = pk_bf16(acc[ct][2], acc[ct][3]);
        *(uint2*)(sU + col * 66 + rh * 16 + quad * 4) = pr;
    }
    __syncthreads();

    // phase 3: mask-driven segmented max, 4 threads/col (16 edges each).
    {
        int j = tid & 127;
        int q4 = tid >> 7;            // 0..3 (wave-uniform)
        int base = q4 * 16;
        const ushort* mrow = sU + j * 66 + base;
        float vals[16];
#pragma unroll
        for (int q = 0; q < 4; ++q) {
            ushort4 mv = *(const ushort4*)(mrow + q * 4);
            vals[q * 4 + 0] = bf2f(mv.x);
            vals[q * 4 + 1] = bf2f(mv.y);
            vals[q * 4 + 2] = bf2f(mv.z);
            vals[q * 4 + 3] = bf2f(mv.w);
        }
        unsigned mlo = __builtin_amdgcn_readfirstlane(sMask[0]);
        unsigned mhi = __builtin_amdgcn_readfirstlane(sMask[1]);
        unsigned b64 = __builtin_amdgcn_readfirstlane(sMask[2]);
        unsigned long long mask = ((unsigned long long)mhi << 32) | mlo;
        unsigned slice = (unsigned)((mask >> base) & 0xFFFFull);
        unsigned nextbit = (q4 == 3) ? (b64 & 1u) : (unsigned)((mask >> (base + 16)) & 1ull);
        unsigned ext = slice | (nextbit << 16);
        bool contFrom = !(ext & 1u);
        float run = 0.f;
        bool first = true;
#pragma unroll
        for (int e3 = 0; e3 < 16; ++e3) {
            float vv2 = vals[e3];
            bool hb = (ext >> e3) & 1u;
            run = (e3 == 0 || hb) ? vv2 : fmaxf(run, vv2);
            bool end = (e3 == 15) || ((ext >> (e3 + 1)) & 1u);
            if (end) {
                int d = sDst[base + e3];
                unsigned en = encf(run);
                unsigned* ap = agg + (size_t)d * HID + j;
                bool useAtomic = (first && contFrom) || ((e3 == 15) && !nextbit);
                if (useAtomic) atomicMax(ap, en);
                else *ap = en;
                first = false;
            }
        }
    }
}

// ---- pooling with fused layer-2 combine: x2 never materialized; 16 slices/graph ----
__global__ __launch_bounds__(256) void pool_kernel(const ushort* __restrict__ x1,
                                                   const unsigned* __restrict__ agg2,
                                                   const float* __restrict__ b2b,
                                                   const int* __restrict__ cnt2,
                                                   const int* __restrict__ batch,
                                                   float* __restrict__ pooled) {
    int g = blockIdx.x >> 4, s = blockIdx.x & 15;
    int tid = threadIdx.x;
    int lo = 0, hi = N_NODES;
    while (lo < hi) { int mid = (lo + hi) >> 1; if (batch[mid] < g) lo = mid + 1; else hi = mid; }
    int start = lo;
    hi = N_NODES;
    while (lo < hi) { int mid = (lo + hi) >> 1; if (batch[mid] < g + 1) lo = mid + 1; else hi = mid; }
    int end = lo;
    int cnt = end - start;
    int b0 = start + (int)((long long)cnt * s / 16);
    int b1 = start + (int)((long long)cnt * (s + 1) / 16);
    if (b1 <= b0) return;
    int j = tid & 127;
    bool isx2 = tid >= 128;
    float bbj = isx2 ? b2b[j] : 0.f;
    float mx = -INFINITY, sm = 0.f;
    for (int n = b0; n < b1; ++n) {
        float xv = bf2f(x1[(size_t)n * HID + j]);
        float vv;
        if (isx2) {
            float a = 0.f;
            if (cnt2[n] > 0) a = decf(agg2[(size_t)n * HID + j]) + bbj;
            vv = fmaxf(a + xv, 0.f);
        } else {
            vv = xv;
        }
        mx = fmaxf(mx, vv);
        sm += vv;
    }
    atomicMax((unsigned*)pooled + (size_t)g * 512 + tid, encf(mx));
    atomicAdd(pooled + (size_t)g * 512 + 256 + tid, sm);
}

// ---- final MLP + log_softmax ----
__global__ __launch_bounds__(128) void final_kernel(const float* __restrict__ pooled,
                                                    const int* __restrict__ batch,
                                                    const float* __restrict__ Wf1,
                                                    const float* __restrict__ bf1,
                                                    const float* __restrict__ Wf2,
                                                    const float* __restrict__ bf2,
                                                    float* __restrict__ out) {
    __shared__ float sP[512];
    __shared__ float sH[128];
    int g = blockIdx.x, tid = threadIdx.x;
    int lo = 0, hi = N_NODES;
    while (lo < hi) { int mid = (lo + hi) >> 1; if (batch[mid] < g) lo = mid + 1; else hi = mid; }
    int start = lo;
    hi = N_NODES;
    while (lo < hi) { int mid = (lo + hi) >> 1; if (batch[mid] < g + 1) lo = mid + 1; else hi = mid; }
    int cnt = lo - start;
    float inv = 1.f / (float)(cnt > 1 ? cnt : 1);
#pragma unroll
    for (int q = 0; q < 4; ++q) {
        int idx = q * 128 + tid;
        float raw;
        if (idx < 256) {
            unsigned e = ((const unsigned*)pooled)[(size_t)g * 512 + idx];
            raw = (e == 0u) ? 0.f : decf(e);
        } else {
            raw = pooled[(size_t)g * 512 + idx] * inv;
        }
        sP[idx] = raw;
    }
    __syncthreads();
    float acc = bf1[tid];
    for (int k = 0; k < 512; ++k) acc = fmaf(sP[k], Wf1[k * HID + tid], acc);
    sH[tid] = fmaxf(acc, 0.f);
    __syncthreads();
    if (tid < 2) {
        float l = bf2[tid];
        for (int k = 0; k < 128; ++k) l = fmaf(sH[k], Wf2[k * 2 + tid], l);
        sP[tid] = l;
    }
    __syncthreads();
    if (tid == 0) {
        float l0 = sP[0], l1 = sP[1];
        float m = fmaxf(l0, l1);
        float ls = m + logf(expf(l0 - m) + expf(l1 - m));
        out[g * 2 + 0] = l0 - ls;
        out[g * 2 + 1] = l1 - ls;
    }
}

extern "C" void kernel_launch(void* const* d_in, const int* in_sizes, int n_in,
                              void* d_out, int out_size, void* d_ws, size_t ws_size,
                              hipStream_t stream) {
    const float* x     = (const float*)d_in[0];
    const float* W_enc = (const float*)d_in[1];
    const float* b_enc = (const float*)d_in[2];
    const float* W0    = (const float*)d_in[3];
    const float* b0    = (const float*)d_in[4];
    const float* W1a   = (const float*)d_in[5];
    const float* b1a   = (const float*)d_in[6];
    const float* W1b   = (const float*)d_in[7];
    const float* b1b   = (const float*)d_in[8];
    const float* W2a   = (const float*)d_in[9];
    const float* b2a   = (const float*)d_in[10];
    const float* W2b   = (const float*)d_in[11];
    const float* b2b   = (const float*)d_in[12];
    const float* Wf1   = (const float*)d_in[13];
    const float* bf1   = (const float*)d_in[14];
    const float* Wf2   = (const float*)d_in[15];
    const float* bf2   = (const float*)d_in[16];
    const int* src1    = (const int*)d_in[17];
    const int* dst1    = (const int*)d_in[18];
    const int* src2    = (const int*)d_in[19];
    const int* dst2    = (const int*)d_in[20];
    const int* batch   = (const int*)d_in[21];

    const size_t NB = (size_t)N_NODES * HID;     // 12.8M elements
    ushort* hbuf  = (ushort*)d_ws;               // h -> x1 (in place, bf16)
    unsigned* agg1 = (unsigned*)(hbuf + NB);     // layer-1 segment-max (u32 encoded)
    unsigned* agg2 = agg1 + NB;                  // layer-2 segment-max
    ushort* ubuf  = (ushort*)(agg2 + NB);        // u bf16
    ushort* vbuf  = ubuf + NB;                   // v bf16
    ushort* WT    = vbuf + NB;                   // 6 x 16384 bf16: Wb1,Wb2,Wu1,Wv1,Wu2,Wv2
    ushort* WbT1 = WT;
    ushort* WbT2 = WT + 1 * HID * HID;
    ushort* WuT1 = WT + 2 * HID * HID;
    ushort* WvT1 = WT + 3 * HID * HID;
    ushort* WuT2 = WT + 4 * HID * HID;
    ushort* WvT2 = WT + 5 * HID * HID;
    float* wkey  = (float*)(WT + 6 * HID * HID);
    float* bias0 = wkey + 128;
    float* xkey  = bias0 + 128;                  // dense per-node key (N_NODES fp32)
    float* pooled = xkey + N_NODES;              // 128*512 fp32
    int* cnt    = (int*)(pooled + 128 * 512);    // 2*N_NODES bucket totals
    int* cursor = cnt + 2 * N_NODES;             // 2*N_NODES (scan1 local-exclusive)
    int* partials = cursor + 2 * N_NODES;        // 1024
    int* srcS = partials + 1024;                 // 2*N_EDGES sorted src
    int* dstS = srcS + 2 * N_EDGES;              // 2*N_EDGES sorted dst (dense expand)
    int* seq  = dstS + 2 * N_EDGES;              // 2*N_EDGES within-bucket rank

    const int edgeGrid = (N_EDGES + 63) / 64;         // 7813 windows of 64
    const int prepGrid = 385 + 256 + BOTH_GRID;       // transpose+prep+zero(pooled)+hist
    const int buildMmGrid = MM_G + A_G + B_G;         // mm1(enc) + expand/zbound + scatter

    hipMemsetAsync(cnt, 0, 2 * N_NODES * sizeof(int), stream);
    prep_hist_kernel<<<prepGrid, 256, 0, stream>>>(W1b, W2b, W1a, W2a, W_enc, b_enc, W0, b0,
                                                   WT, wkey, bias0, pooled, dst1, dst2, cnt, seq);
    scan1_kernel<<<SCAN1_B, 256, 0, stream>>>(cnt, cursor, partials);
    scan2_kernel<<<1, 1024, 0, stream>>>(partials);

    // ---- fused: mm1 (inline encode) || CSR build ----
    build_mm_kernel<<<buildMmGrid, 512, 0, stream>>>(x, W0, wkey, bias0, hbuf, xkey,
                                                     WuT1, WvT1, b1a, ubuf, vbuf,
                                                     src1, dst1, src2, dst2, cnt, cursor,
                                                     partials, seq, srcS, dstS, agg1, agg2);

    // ---- layer 1 edge ----
    edge_kernel<<<edgeGrid, 512, 0, stream>>>(ubuf, vbuf, xkey, srcS, dstS, WbT1,
                                              W1a + 256 * HID, agg1);

    // ---- layer 2 (mm fuses layer-1 combine; writes x1 to hbuf) ----
    mm_mfma_dual_kernel<<<MM_G, 512, 0, stream>>>(hbuf, agg1, cnt, b1b, hbuf,
                                                  WuT2, WvT2, b2a, ubuf, vbuf, N_NODES);
    edge_kernel<<<edgeGrid, 512, 0, stream>>>(ubuf, vbuf, xkey, srcS + N_EDGES, dstS + N_EDGES,
                                              WbT2, W2a + 256 * HID, agg2);

    // ---- pooling (layer-2 combine fused; pooled zeroed by prep_hist) + head ----
    pool_kernel<<<N_GRAPHS * 16, 256, 0, stream>>>(hbuf, agg2, b2b, cnt + N_NODES, batch, pooled);
    final_kernel<<<N_GRAPHS, 128, 0, stream>>>(pooled, batch, Wf1, bf1, Wf2, bf2, (float*)d_out);
}

// Round 14
// 441.873 us; speedup vs baseline: 1.1214x; 1.0484x over previous
//
#include <hip/hip_runtime.h>
#include <cstdint>

#define N_NODES 100000
#define N_EDGES 500000
#define N_GRAPHS 128
#define HID 128
#define SCAN1_B ((2 * N_NODES + 255) / 256)   // 782 blocks over concatenated counts
#define BOTH_GRID ((2 * N_EDGES + 255) / 256) // 3907 blocks over concatenated edges
#define MM_G ((N_NODES + 127) / 128)          // 782 mm blocks
#define A_G ((2 * N_NODES + 511) / 512)       // 391 expand/zbound blocks (512 thr)
#define B_G ((2 * N_EDGES + 511) / 512)       // 1954 scatter blocks (512 thr)

typedef __attribute__((ext_vector_type(8))) short short8;
typedef __attribute__((ext_vector_type(4))) float f32x4;

// ---- monotone float<->uint encoding for max; enc==0 marks "never written" ----
__device__ __forceinline__ unsigned encf(float f) {
    unsigned u = __float_as_uint(f);
    return (u & 0x80000000u) ? ~u : (u | 0x80000000u);
}
__device__ __forceinline__ float decf(unsigned e) {
    unsigned u = (e & 0x80000000u) ? (e & 0x7FFFFFFFu) : ~e;
    return __uint_as_float(u);
}
// ---- hardware packed f32->bf16 (RNE, src0->low half): one instruction vs
//      ~10 VALU ops for the manual +0x7fff+lsb round (bit-identical RNE). ----
__device__ __forceinline__ unsigned cvt_pk_bf16(float lo, float hi) {
    unsigned r;
    asm("v_cvt_pk_bf16_f32 %0, %1, %2" : "=v"(r) : "v"(lo), "v"(hi));
    return r;
}
__device__ __forceinline__ ushort bf16r(float f) {
    unsigned u = __float_as_uint(f);
    return (ushort)((u + 0x7fffu + ((u >> 16) & 1u)) >> 16);
}
__device__ __forceinline__ float bf2f(ushort h) {
    return __uint_as_float((unsigned)h << 16);
}

// ---- D1: transpose weights + prep + zero pooled + HIST (fused). ----
__global__ __launch_bounds__(256) void prep_hist_kernel(const float* __restrict__ W1b,
                                                        const float* __restrict__ W2b,
                                                        const float* __restrict__ W1a,
                                                        const float* __restrict__ W2a,
                                                        const float* __restrict__ W_enc,
                                                        const float* __restrict__ b_enc,
                                                        const float* __restrict__ W0,
                                                        const float* __restrict__ b0,
                                                        ushort* __restrict__ WT,
                                                        float* __restrict__ wkey,
                                                        float* __restrict__ bias0,
                                                        float* __restrict__ pooled,
                                                        const int* __restrict__ dst1,
                                                        const int* __restrict__ dst2,
                                                        int* __restrict__ cnt,
                                                        int* __restrict__ seq) {
    int blk = blockIdx.x;
    int tid = threadIdx.x;
    if (blk >= 641) {   // hist
        int e = (blk - 641) * 256 + tid;
        if (e < N_EDGES) seq[e] = atomicAdd(&cnt[dst1[e]], 1);
        else if (e < 2 * N_EDGES) seq[e] = atomicAdd(&cnt[N_NODES + dst2[e - N_EDGES]], 1);
        return;
    }
    if (blk >= 385) {   // zero pooled (exactly 256*256 = 65536 floats)
        pooled[(blk - 385) * 256 + tid] = 0.f;
        return;
    }
    if (blk == 384) {   // prep
        if (tid < HID) {
            float wk = 0.f, bk = b0[tid];
            for (int k = 0; k < 32; ++k) {
                float w = W0[(15 + k) * HID + tid];
                wk += W_enc[k] * w;
                bk += b_enc[k] * w;
            }
            wkey[tid] = wk;
            bias0[tid] = bk;
        }
        return;
    }
    int m = blk >> 6;
    int i = (blk & 63) * 256 + tid;   // i = n*128 + k
    int n = i >> 7, k = i & 127;
    int src = k * HID + n;
    float v;
    switch (m) {
        case 0: v = W1b[src]; break;
        case 1: v = W2b[src]; break;
        case 2: v = W1a[src]; break;
        case 3: v = W1a[HID * HID + src] - W1a[src]; break;
        case 4: v = W2a[src]; break;
        default: v = W2a[HID * HID + src] - W2a[src]; break;
    }
    WT[m * HID * HID + i] = bf16r(v);
}

__global__ __launch_bounds__(256) void scan1_kernel(const int* __restrict__ cnt,
                                                    int* __restrict__ cursor,
                                                    int* __restrict__ partials) {
    __shared__ int tmp[256];
    int tid = threadIdx.x;
    int gid = blockIdx.x * 256 + tid;
    int v = (gid < 2 * N_NODES) ? cnt[gid] : 0;
    tmp[tid] = v;
    __syncthreads();
#pragma unroll
    for (int off = 1; off < 256; off <<= 1) {
        int t = (tid >= off) ? tmp[tid - off] : 0;
        __syncthreads();
        tmp[tid] += t;
        __syncthreads();
    }
    if (gid < 2 * N_NODES) cursor[gid] = tmp[tid] - v;   // local exclusive
    if (tid == 255) partials[blockIdx.x] = tmp[255];
}

__global__ __launch_bounds__(1024) void scan2_kernel(int* __restrict__ partials) {
    __shared__ int tmp[1024];
    int tid = threadIdx.x;
    int v = (tid < SCAN1_B) ? partials[tid] : 0;
    tmp[tid] = v;
    __syncthreads();
#pragma unroll
    for (int off = 1; off < 1024; off <<= 1) {
        int t = (tid >= off) ? tmp[tid - off] : 0;
        __syncthreads();
        tmp[tid] += t;
        __syncthreads();
    }
    if (tid < SCAN1_B) partials[tid] = tmp[tid] - v;  // exclusive
}

// ---- D4 fused: [mm1 with INLINE ENCODE] + [CSR build] ----
__global__ __launch_bounds__(512, 4) void build_mm_kernel(const float* __restrict__ x,
                                                          const float* __restrict__ W0,
                                                          const float* __restrict__ wkey,
                                                          const float* __restrict__ bias0,
                                                          ushort* __restrict__ h,
                                                          float* __restrict__ xkey,
                                                          const ushort* __restrict__ WuT,
                                                          const ushort* __restrict__ WvT,
                                                          const float* __restrict__ bv,
                                                          ushort* __restrict__ outu,
                                                          ushort* __restrict__ outv,
                                                          const int* __restrict__ src1,
                                                          const int* __restrict__ dst1,
                                                          const int* __restrict__ src2,
                                                          const int* __restrict__ dst2,
                                                          const int* __restrict__ cnt,
                                                          const int* __restrict__ cursor,
                                                          const int* __restrict__ partials,
                                                          const int* __restrict__ seq,
                                                          int* __restrict__ srcS,
                                                          int* __restrict__ dstS,
                                                          unsigned* __restrict__ agg1,
                                                          unsigned* __restrict__ agg2) {
    __shared__ ushort sH[128 * 136];    // A-tile, then reused for D-restage
    __shared__ ushort sWT[128 * 136];   // Wu, then Wv
    int blk = blockIdx.x;
    int tid = threadIdx.x;

    if (blk >= MM_G) {
        int zb = blk - MM_G;
        if (zb < A_G) {   // expand dst + zero boundary agg rows
            int gid = zb * 512 + tid;
            if (gid >= 2 * N_NODES) return;
            int c = cnt[gid];
            if (c == 0) return;
            int o = cursor[gid] + partials[gid >> 8];
            int layer = gid >= N_NODES;
            int d = gid - layer * N_NODES;
            for (int i = 0; i < c; ++i) dstS[o + i] = d;
            bool spans = (o >> 4) != ((o + c - 1) >> 4);
            bool tail = (o + c == N_EDGES) || (o + c == 2 * N_EDGES);
            if (spans || tail) {
                unsigned* agg = layer ? agg2 : agg1;
                uint4* ap = (uint4*)(agg + (size_t)d * HID);
#pragma unroll
                for (int i = 0; i < 32; ++i) ap[i] = make_uint4(0u, 0u, 0u, 0u);
            }
            return;
        }
        int e = (zb - A_G) * 512 + tid;   // scatter src (atomic-free)
        int s, idx;
        if (e < N_EDGES) { s = src1[e]; idx = dst1[e]; }
        else if (e < 2 * N_EDGES) { s = src2[e - N_EDGES]; idx = N_NODES + dst2[e - N_EDGES]; }
        else return;
        int pos = cursor[idx] + partials[idx >> 8] + seq[e];
        srcS[pos] = s;
        return;
    }

    // ---- mm1 with inline encode ----
    int n0 = blk * 128;
#pragma unroll
    for (int q = 0; q < 4; ++q) {
        int c = q * 512 + tid;
        int r = c >> 4, off = (c & 15) << 3;
        int n = n0 + r;
        uint4 vv = make_uint4(0, 0, 0, 0);
        if (n < N_NODES) {
            const float* xr = x + n * 16;
            float k0 = xr[0];
            if (off == 0) xkey[n] = k0;
            float xf[15];
#pragma unroll
            for (int f = 0; f < 15; ++f) xf[f] = xr[1 + f];
            unsigned ow[4];
#pragma unroll
            for (int p = 0; p < 4; ++p) {
                int c0 = off + 2 * p;
                float a0 = bias0[c0] + k0 * wkey[c0];
                float a1 = bias0[c0 + 1] + k0 * wkey[c0 + 1];
#pragma unroll
                for (int f = 0; f < 15; ++f) {
                    float2 w2 = *(const float2*)(W0 + f * HID + c0);
                    a0 = fmaf(xf[f], w2.x, a0);
                    a1 = fmaf(xf[f], w2.y, a1);
                }
                ow[p] = cvt_pk_bf16(fmaxf(a0, 0.f), fmaxf(a1, 0.f));
            }
            vv = make_uint4(ow[0], ow[1], ow[2], ow[3]);
            *(uint4*)(h + (size_t)n * HID + off) = vv;
        }
        *(uint4*)(sH + r * 136 + off) = vv;
    }
    // stage Wu
#pragma unroll
    for (int q = 0; q < 4; ++q) {
        int c = q * 512 + tid;
        int nn = c >> 4, off = (c & 15) << 3;
        *(uint4*)(sWT + nn * 136 + off) = *(const uint4*)(WuT + nn * 128 + off);
    }
    __syncthreads();

    int lane = tid & 63, wv = tid >> 6;
    int l15 = lane & 15, quad = lane >> 4;
    int ch = wv & 1, rh = wv >> 1;

    short8 afr[2][4];
#pragma unroll
    for (int rr = 0; rr < 2; ++rr) {
        const ushort* ab = sH + (rh * 32 + rr * 16 + l15) * 136 + quad * 8;
#pragma unroll
        for (int kc = 0; kc < 4; ++kc)
            afr[rr][kc] = *(const short8*)(ab + kc * 32);
    }

#pragma unroll
    for (int pass = 0; pass < 2; ++pass) {
        ushort* out = pass ? outv : outu;
        f32x4 acc[2][4];
#pragma unroll
        for (int rr = 0; rr < 2; ++rr)
#pragma unroll
            for (int ct = 0; ct < 4; ++ct) acc[rr][ct] = (f32x4){0.f, 0.f, 0.f, 0.f};
#pragma unroll
        for (int kc = 0; kc < 4; ++kc) {
#pragma unroll
            for (int ct = 0; ct < 4; ++ct) {
                short8 bfr = *(const short8*)(sWT + ((ch * 4 + ct) * 16 + l15) * 136 + quad * 8 + kc * 32);
                acc[0][ct] = __builtin_amdgcn_mfma_f32_16x16x32_bf16(afr[0][kc], bfr, acc[0][ct], 0, 0, 0);
                acc[1][ct] = __builtin_amdgcn_mfma_f32_16x16x32_bf16(afr[1][kc], bfr, acc[1][ct], 0, 0, 0);
            }
        }
        __syncthreads();   // sWT + sH(afr) reads done
#pragma unroll
        for (int ct = 0; ct < 4; ++ct) {
            int col = (ch * 4 + ct) * 16 + l15;
            float bb = pass ? bv[col] : 0.f;
#pragma unroll
            for (int rr = 0; rr < 2; ++rr) {
                int rowb = rh * 32 + rr * 16 + quad * 4;
                unsigned p01 = cvt_pk_bf16(acc[rr][ct][0] + bb, acc[rr][ct][1] + bb);
                unsigned p23 = cvt_pk_bf16(acc[rr][ct][2] + bb, acc[rr][ct][3] + bb);
                sH[(rowb + 0) * 136 + col] = (ushort)p01;
                sH[(rowb + 1) * 136 + col] = (ushort)(p01 >> 16);
                sH[(rowb + 2) * 136 + col] = (ushort)p23;
                sH[(rowb + 3) * 136 + col] = (ushort)(p23 >> 16);
            }
        }
        if (pass == 0) {   // restage Wv over sWT (reads drained by the barrier above)
#pragma unroll
            for (int q = 0; q < 4; ++q) {
                int c = q * 512 + tid;
                int nn = c >> 4, off = (c & 15) << 3;
                *(uint4*)(sWT + nn * 136 + off) = *(const uint4*)(WvT + nn * 128 + off);
            }
        }
        __syncthreads();
#pragma unroll
        for (int q = 0; q < 4; ++q) {
            int c = q * 512 + tid;
            int r = c >> 4, off = (c & 15) << 3;
            int m = n0 + r;
            if (m < N_NODES)
                *(uint4*)(out + (size_t)m * HID + off) = *(const uint4*)(sH + r * 136 + off);
        }
    }
}

// ---- dual MFMA (used for layer 2: fused layer-1 combine) ----
__global__ __launch_bounds__(512, 4) void mm_mfma_dual_kernel(const ushort* __restrict__ in,
                                                              const unsigned* __restrict__ aggin,
                                                              const int* __restrict__ cntin,
                                                              const float* __restrict__ baddin,
                                                              ushort* __restrict__ xout,
                                                              const ushort* __restrict__ WuT,
                                                              const ushort* __restrict__ WvT,
                                                              const float* __restrict__ bv,
                                                              ushort* __restrict__ outu,
                                                              ushort* __restrict__ outv, int nrows) {
    __shared__ ushort sH[128 * 136];    // A-tile, then reused for D-restage
    __shared__ ushort sWT[128 * 136];   // Wu, then Wv
    int tid = threadIdx.x;
    int n0 = blockIdx.x * 128;
#pragma unroll
    for (int q = 0; q < 4; ++q) {
        int c = q * 512 + tid;
        int r = c >> 4, off = (c & 15) << 3;
        int n = n0 + r;
        uint4 vv = make_uint4(0, 0, 0, 0);
        if (n < nrows) {
            uint4 hv = *(const uint4*)(in + (size_t)n * HID + off);
            float add[8];
#pragma unroll
            for (int p = 0; p < 8; ++p) add[p] = 0.f;
            if (cntin[n] > 0) {
                uint4 e0 = *(const uint4*)(aggin + (size_t)n * HID + off);
                uint4 e1 = *(const uint4*)(aggin + (size_t)n * HID + off + 4);
                float4 bb0 = *(const float4*)(baddin + off);
                float4 bb1 = *(const float4*)(baddin + off + 4);
                add[0] = decf(e0.x) + bb0.x; add[1] = decf(e0.y) + bb0.y;
                add[2] = decf(e0.z) + bb0.z; add[3] = decf(e0.w) + bb0.w;
                add[4] = decf(e1.x) + bb1.x; add[5] = decf(e1.y) + bb1.y;
                add[6] = decf(e1.z) + bb1.z; add[7] = decf(e1.w) + bb1.w;
            }
            unsigned hw[4] = {hv.x, hv.y, hv.z, hv.w};
            unsigned ow[4];
#pragma unroll
            for (int p = 0; p < 4; ++p) {
                float lo = __uint_as_float(hw[p] << 16);
                float hi = __uint_as_float(hw[p] & 0xffff0000u);
                float r0 = fmaxf(add[2 * p] + lo, 0.f);
                float r1 = fmaxf(add[2 * p + 1] + hi, 0.f);
                ow[p] = cvt_pk_bf16(r0, r1);
            }
            vv = make_uint4(ow[0], ow[1], ow[2], ow[3]);
            *(uint4*)(xout + (size_t)n * HID + off) = vv;
        }
        *(uint4*)(sH + r * 136 + off) = vv;
    }
    // stage Wu
#pragma unroll
    for (int q = 0; q < 4; ++q) {
        int c = q * 512 + tid;
        int nn = c >> 4, off = (c & 15) << 3;
        *(uint4*)(sWT + nn * 136 + off) = *(const uint4*)(WuT + nn * 128 + off);
    }
    __syncthreads();

    int lane = tid & 63, wv = tid >> 6;
    int l15 = lane & 15, quad = lane >> 4;
    int ch = wv & 1, rh = wv >> 1;

    short8 afr[2][4];
#pragma unroll
    for (int rr = 0; rr < 2; ++rr) {
        const ushort* ab = sH + (rh * 32 + rr * 16 + l15) * 136 + quad * 8;
#pragma unroll
        for (int kc = 0; kc < 4; ++kc)
            afr[rr][kc] = *(const short8*)(ab + kc * 32);
    }

#pragma unroll
    for (int pass = 0; pass < 2; ++pass) {
        ushort* out = pass ? outv : outu;
        f32x4 acc[2][4];
#pragma unroll
        for (int rr = 0; rr < 2; ++rr)
#pragma unroll
            for (int ct = 0; ct < 4; ++ct) acc[rr][ct] = (f32x4){0.f, 0.f, 0.f, 0.f};
#pragma unroll
        for (int kc = 0; kc < 4; ++kc) {
#pragma unroll
            for (int ct = 0; ct < 4; ++ct) {
                short8 bfr = *(const short8*)(sWT + ((ch * 4 + ct) * 16 + l15) * 136 + quad * 8 + kc * 32);
                acc[0][ct] = __builtin_amdgcn_mfma_f32_16x16x32_bf16(afr[0][kc], bfr, acc[0][ct], 0, 0, 0);
                acc[1][ct] = __builtin_amdgcn_mfma_f32_16x16x32_bf16(afr[1][kc], bfr, acc[1][ct], 0, 0, 0);
            }
        }
        __syncthreads();   // sWT + sH(afr) reads done
#pragma unroll
        for (int ct = 0; ct < 4; ++ct) {
            int col = (ch * 4 + ct) * 16 + l15;
            float bb = pass ? bv[col] : 0.f;
#pragma unroll
            for (int rr = 0; rr < 2; ++rr) {
                int rowb = rh * 32 + rr * 16 + quad * 4;
                unsigned p01 = cvt_pk_bf16(acc[rr][ct][0] + bb, acc[rr][ct][1] + bb);
                unsigned p23 = cvt_pk_bf16(acc[rr][ct][2] + bb, acc[rr][ct][3] + bb);
                sH[(rowb + 0) * 136 + col] = (ushort)p01;
                sH[(rowb + 1) * 136 + col] = (ushort)(p01 >> 16);
                sH[(rowb + 2) * 136 + col] = (ushort)p23;
                sH[(rowb + 3) * 136 + col] = (ushort)(p23 >> 16);
            }
        }
        if (pass == 0) {   // restage Wv over sWT (reads drained by the barrier above)
#pragma unroll
            for (int q = 0; q < 4; ++q) {
                int c = q * 512 + tid;
                int nn = c >> 4, off = (c & 15) << 3;
                *(uint4*)(sWT + nn * 136 + off) = *(const uint4*)(WvT + nn * 128 + off);
            }
        }
        __syncthreads();
#pragma unroll
        for (int q = 0; q < 4; ++q) {
            int c = q * 512 + tid;
            int r = c >> 4, off = (c & 15) << 3;
            int m = n0 + r;
            if (m < nrows)
                *(uint4*)(out + (size_t)m * HID + off) = *(const uint4*)(sH + r * 136 + off);
        }
    }
}

// ---- edge conv: bf16 MFMA, 64-edge dst-sorted windows, 512 threads.
//      hardware cvt_pk_bf16 pack + bijective XCD-chunked blockIdx swizzle
//      (consecutive windows share v-rows via dst-sort; chunking keeps that
//      reuse inside one XCD's L2). Order independence: boundary segments use
//      atomicMax + pre-zeroed rows, so the swizzle cannot change results. ----
__global__ __launch_bounds__(512, 6) void edge_kernel(const ushort* __restrict__ u,
                                                      const ushort* __restrict__ v,
                                                      const float* __restrict__ xkey,
                                                      const int* __restrict__ srcS,
                                                      const int* __restrict__ dstS,
                                                      const ushort* __restrict__ WbT,
                                                      const float* __restrict__ wlast,
                                                      unsigned* __restrict__ agg) {
    __shared__ ushort sWT[128 * 136];   // 34816 B: WbT[n][k] bf16, padded stride
    __shared__ ushort sU[64 * 136];     // 17408 B union: t[64][136] then msgT[128][66]
    __shared__ int sDst[64];
    __shared__ int sBnd[2];             // [0]=dst before window, [1]=dst after window
    __shared__ unsigned sMask[3];       // head-flag mask lo/hi + head64 flag
    int tid = threadIdx.x;

    // bijective XCD chunking (nwg % 8 != 0 -> m204 variant)
    int nwg = gridDim.x;
    int orig = blockIdx.x;
    int qq = nwg >> 3, rr8 = nwg & 7;
    int xcd = orig & 7, idx = orig >> 3;
    int wgid = (xcd < rr8 ? xcd * (qq + 1) : rr8 * (qq + 1) + (xcd - rr8) * qq) + idx;
    int w0 = wgid * 64;

    // W stage: 2048 uint4 over 512 threads = 4 each (L2-hot 32KB)
#pragma unroll
    for (int q = 0; q < 4; ++q) {
        int c = q * 512 + tid;
        int n = c >> 4, off = (c & 15) << 3;
        *(uint4*)(sWT + n * 136 + off) = *(const uint4*)(WbT + n * 128 + off);
    }

    int eloc = tid >> 3;
    int sub = tid & 7;
    int kb = sub << 4;
    int lane = tid & 63, wv = tid >> 6;
    int l15 = lane & 15, quad = lane >> 4;
    int ch = wv & 1, rh = wv >> 1;

    // loop-invariant wlast slice for this thread's 16 columns -> registers
    float wreg[16];
    {
        const float4* wr4 = (const float4*)(wlast + kb);
#pragma unroll
        for (int q = 0; q < 4; ++q) {
            float4 wq = wr4[q];
            wreg[q * 4 + 0] = wq.x; wreg[q * 4 + 1] = wq.y;
            wreg[q * 4 + 2] = wq.z; wreg[q * 4 + 3] = wq.w;
        }
    }

    // phase 1: per-thread meta + gather + compute t
    {
        int e = w0 + eloc;
        if (e >= N_EDGES) e = N_EDGES - 1;   // clamp: idempotent under max
        int sx = srcS[e], sy = dstS[e];
        if (sub == 0) sDst[eloc] = sy;
        if (tid < 2) {
            int eb = (tid == 0) ? (w0 - 1) : (w0 + 64);
            sBnd[tid] = (eb >= 0 && eb < N_EDGES) ? dstS[eb] : -1;
        }
        float kd = xkey[sx] - xkey[sy];
        const uint4* ur = (const uint4*)(u + (size_t)sx * HID + kb);
        const uint4* vr = (const uint4*)(v + (size_t)sy * HID + kb);
        uint4 uu[2], vvv[2];
        uu[0] = ur[0]; uu[1] = ur[1];
        vvv[0] = vr[0]; vvv[1] = vr[1];
#pragma unroll
        for (int q = 0; q < 2; ++q) {
            unsigned pu[4] = {uu[q].x, uu[q].y, uu[q].z, uu[q].w};
            unsigned pv[4] = {vvv[q].x, vvv[q].y, vvv[q].z, vvv[q].w};
            unsigned pk[4];
#pragma unroll
            for (int p = 0; p < 4; ++p) {
                float a0 = __uint_as_float(pu[p] << 16) + __uint_as_float(pv[p] << 16);
                float a1 = __uint_as_float(pu[p] & 0xffff0000u) + __uint_as_float(pv[p] & 0xffff0000u);
                a0 = fmaf(kd, wreg[q * 8 + 2 * p], a0);
                a1 = fmaf(kd, wreg[q * 8 + 2 * p + 1], a1);
                a0 = fmaxf(a0, 0.1f * a0);   // leaky relu
                a1 = fmaxf(a1, 0.1f * a1);
                pk[p] = cvt_pk_bf16(a0, a1);
            }
            uint4 o; o.x = pk[0]; o.y = pk[1]; o.z = pk[2]; o.w = pk[3];
            *(uint4*)(sU + eloc * 136 + kb + q * 8) = o;
        }
    }
    __syncthreads();   // W-stage + t + sDst + sBnd ready

    // segment head flags: computed ONCE by wave 0 (uniform across columns)
    if (tid < 64) {
        int dprev = (tid == 0) ? sBnd[0] : sDst[tid - 1];
        unsigned long long m = __ballot(sDst[tid] != dprev);
        if (tid == 0) { sMask[0] = (unsigned)m; sMask[1] = (unsigned)(m >> 32); }
        if (tid == 63) sMask[2] = (sDst[63] != sBnd[1]) ? 1u : 0u;
    }

    // phase 2: MFMA. wave wv: rows (wv>>1)*16..+15, cols (wv&1)*64..+63
    short8 afr[4];
    {
        const ushort* ab = sU + (rh * 16 + l15) * 136 + quad * 8;
#pragma unroll
        for (int kc = 0; kc < 4; ++kc)
            afr[kc] = *(const short8*)(ab + kc * 32);
    }
    f32x4 acc[4];
#pragma unroll
    for (int ct = 0; ct < 4; ++ct) acc[ct] = (f32x4){0.f, 0.f, 0.f, 0.f};
#pragma unroll
    for (int kc = 0; kc < 4; ++kc) {
#pragma unroll
        for (int ct = 0; ct < 4; ++ct) {
            short8 bfr = *(const short8*)(sWT + ((ch * 4 + ct) * 16 + l15) * 136 + quad * 8 + kc * 32);
            acc[ct] = __builtin_amdgcn_mfma_f32_16x16x32_bf16(afr[kc], bfr, acc[ct], 0, 0, 0);
        }
    }
    __syncthreads();   // all t reads done -> sU reusable

    // epilogue: msgT[col][edge] bf16, stride 66 (odd dword stride -> conflict-free)
#pragma unroll
    for (int ct = 0; ct < 4; ++ct) {
        int col = (ch * 4 + ct) * 16 + l15;
        uint2 pr;
        pr.x = cvt_pk_bf16(acc[ct][0], acc[ct][1]);
        pr.y = cvt_pk_bf16(acc[ct][2], acc[ct][3]);
        *(uint2*)(sU + col * 66 + rh * 16 + quad * 4) = pr;
    }
    __syncthreads();

    // phase 3: mask-driven segmented max, 4 threads/col (16 edges each).
    {
        int j = tid & 127;
        int q4 = tid >> 7;            // 0..3 (wave-uniform)
        int base = q4 * 16;
        const ushort* mrow = sU + j * 66 + base;
        float vals[16];
#pragma unroll
        for (int q = 0; q < 4; ++q) {
            ushort4 mv = *(const ushort4*)(mrow + q * 4);
            vals[q * 4 + 0] = bf2f(mv.x);
            vals[q * 4 + 1] = bf2f(mv.y);
            vals[q * 4 + 2] = bf2f(mv.z);
            vals[q * 4 + 3] = bf2f(mv.w);
        }
        unsigned mlo = __builtin_amdgcn_readfirstlane(sMask[0]);
        unsigned mhi = __builtin_amdgcn_readfirstlane(sMask[1]);
        unsigned b64 = __builtin_amdgcn_readfirstlane(sMask[2]);
        unsigned long long mask = ((unsigned long long)mhi << 32) | mlo;
        unsigned slice = (unsigned)((mask >> base) & 0xFFFFull);
        unsigned nextbit = (q4 == 3) ? (b64 & 1u) : (unsigned)((mask >> (base + 16)) & 1ull);
        unsigned ext = slice | (nextbit << 16);
        bool contFrom = !(ext & 1u);
        float run = 0.f;
        bool first = true;
#pragma unroll
        for (int e3 = 0; e3 < 16; ++e3) {
            float vv2 = vals[e3];
            bool hb = (ext >> e3) & 1u;
            run = (e3 == 0 || hb) ? vv2 : fmaxf(run, vv2);
            bool end = (e3 == 15) || ((ext >> (e3 + 1)) & 1u);
            if (end) {
                int d = sDst[base + e3];
                unsigned en = encf(run);
                unsigned* ap = agg + (size_t)d * HID + j;
                bool useAtomic = (first && contFrom) || ((e3 == 15) && !nextbit);
                if (useAtomic) atomicMax(ap, en);
                else *ap = en;
                first = false;
            }
        }
    }
}

// ---- pooling with fused layer-2 combine: x2 never materialized; 16 slices/graph ----
__global__ __launch_bounds__(256) void pool_kernel(const ushort* __restrict__ x1,
                                                   const unsigned* __restrict__ agg2,
                                                   const float* __restrict__ b2b,
                                                   const int* __restrict__ cnt2,
                                                   const int* __restrict__ batch,
                                                   float* __restrict__ pooled) {
    int g = blockIdx.x >> 4, s = blockIdx.x & 15;
    int tid = threadIdx.x;
    int lo = 0, hi = N_NODES;
    while (lo < hi) { int mid = (lo + hi) >> 1; if (batch[mid] < g) lo = mid + 1; else hi = mid; }
    int start = lo;
    hi = N_NODES;
    while (lo < hi) { int mid = (lo + hi) >> 1; if (batch[mid] < g + 1) lo = mid + 1; else hi = mid; }
    int end = lo;
    int cnt = end - start;
    int b0 = start + (int)((long long)cnt * s / 16);
    int b1 = start + (int)((long long)cnt * (s + 1) / 16);
    if (b1 <= b0) return;
    int j = tid & 127;
    bool isx2 = tid >= 128;
    float bbj = isx2 ? b2b[j] : 0.f;
    float mx = -INFINITY, sm = 0.f;
    for (int n = b0; n < b1; ++n) {
        float xv = bf2f(x1[(size_t)n * HID + j]);
        float vv;
        if (isx2) {
            float a = 0.f;
            if (cnt2[n] > 0) a = decf(agg2[(size_t)n * HID + j]) + bbj;
            vv = fmaxf(a + xv, 0.f);
        } else {
            vv = xv;
        }
        mx = fmaxf(mx, vv);
        sm += vv;
    }
    atomicMax((unsigned*)pooled + (size_t)g * 512 + tid, encf(mx));
    atomicAdd(pooled + (size_t)g * 512 + 256 + tid, sm);
}

// ---- final MLP + log_softmax ----
__global__ __launch_bounds__(128) void final_kernel(const float* __restrict__ pooled,
                                                    const int* __restrict__ batch,
                                                    const float* __restrict__ Wf1,
                                                    const float* __restrict__ bf1,
                                                    const float* __restrict__ Wf2,
                                                    const float* __restrict__ bf2,
                                                    float* __restrict__ out) {
    __shared__ float sP[512];
    __shared__ float sH[128];
    int g = blockIdx.x, tid = threadIdx.x;
    int lo = 0, hi = N_NODES;
    while (lo < hi) { int mid = (lo + hi) >> 1; if (batch[mid] < g) lo = mid + 1; else hi = mid; }
    int start = lo;
    hi = N_NODES;
    while (lo < hi) { int mid = (lo + hi) >> 1; if (batch[mid] < g + 1) lo = mid + 1; else hi = mid; }
    int cnt = lo - start;
    float inv = 1.f / (float)(cnt > 1 ? cnt : 1);
#pragma unroll
    for (int q = 0; q < 4; ++q) {
        int idx = q * 128 + tid;
        float raw;
        if (idx < 256) {
            unsigned e = ((const unsigned*)pooled)[(size_t)g * 512 + idx];
            raw = (e == 0u) ? 0.f : decf(e);
        } else {
            raw = pooled[(size_t)g * 512 + idx] * inv;
        }
        sP[idx] = raw;
    }
    __syncthreads();
    float acc = bf1[tid];
    for (int k = 0; k < 512; ++k) acc = fmaf(sP[k], Wf1[k * HID + tid], acc);
    sH[tid] = fmaxf(acc, 0.f);
    __syncthreads();
    if (tid < 2) {
        float l = bf2[tid];
        for (int k = 0; k < 128; ++k) l = fmaf(sH[k], Wf2[k * 2 + tid], l);
        sP[tid] = l;
    }
    __syncthreads();
    if (tid == 0) {
        float l0 = sP[0], l1 = sP[1];
        float m = fmaxf(l0, l1);
        float ls = m + logf(expf(l0 - m) + expf(l1 - m));
        out[g * 2 + 0] = l0 - ls;
        out[g * 2 + 1] = l1 - ls;
    }
}

extern "C" void kernel_launch(void* const* d_in, const int* in_sizes, int n_in,
                              void* d_out, int out_size, void* d_ws, size_t ws_size,
                              hipStream_t stream) {
    const float* x     = (const float*)d_in[0];
    const float* W_enc = (const float*)d_in[1];
    const float* b_enc = (const float*)d_in[2];
    const float* W0    = (const float*)d_in[3];
    const float* b0    = (const float*)d_in[4];
    const float* W1a   = (const float*)d_in[5];
    const float* b1a   = (const float*)d_in[6];
    const float* W1b   = (const float*)d_in[7];
    const float* b1b   = (const float*)d_in[8];
    const float* W2a   = (const float*)d_in[9];
    const float* b2a   = (const float*)d_in[10];
    const float* W2b   = (const float*)d_in[11];
    const float* b2b   = (const float*)d_in[12];
    const float* Wf1   = (const float*)d_in[13];
    const float* bf1   = (const float*)d_in[14];
    const float* Wf2   = (const float*)d_in[15];
    const float* bf2   = (const float*)d_in[16];
    const int* src1    = (const int*)d_in[17];
    const int* dst1    = (const int*)d_in[18];
    const int* src2    = (const int*)d_in[19];
    const int* dst2    = (const int*)d_in[20];
    const int* batch   = (const int*)d_in[21];

    const size_t NB = (size_t)N_NODES * HID;     // 12.8M elements
    ushort* hbuf  = (ushort*)d_ws;               // h -> x1 (in place, bf16)
    unsigned* agg1 = (unsigned*)(hbuf + NB);     // layer-1 segment-max (u32 encoded)
    unsigned* agg2 = agg1 + NB;                  // layer-2 segment-max
    ushort* ubuf  = (ushort*)(agg2 + NB);        // u bf16
    ushort* vbuf  = ubuf + NB;                   // v bf16
    ushort* WT    = vbuf + NB;                   // 6 x 16384 bf16: Wb1,Wb2,Wu1,Wv1,Wu2,Wv2
    ushort* WbT1 = WT;
    ushort* WbT2 = WT + 1 * HID * HID;
    ushort* WuT1 = WT + 2 * HID * HID;
    ushort* WvT1 = WT + 3 * HID * HID;
    ushort* WuT2 = WT + 4 * HID * HID;
    ushort* WvT2 = WT + 5 * HID * HID;
    float* wkey  = (float*)(WT + 6 * HID * HID);
    float* bias0 = wkey + 128;
    float* xkey  = bias0 + 128;                  // dense per-node key (N_NODES fp32)
    float* pooled = xkey + N_NODES;              // 128*512 fp32
    int* cnt    = (int*)(pooled + 128 * 512);    // 2*N_NODES bucket totals
    int* cursor = cnt + 2 * N_NODES;             // 2*N_NODES (scan1 local-exclusive)
    int* partials = cursor + 2 * N_NODES;        // 1024
    int* srcS = partials + 1024;                 // 2*N_EDGES sorted src
    int* dstS = srcS + 2 * N_EDGES;              // 2*N_EDGES sorted dst (dense expand)
    int* seq  = dstS + 2 * N_EDGES;              // 2*N_EDGES within-bucket rank

    const int edgeGrid = (N_EDGES + 63) / 64;         // 7813 windows of 64
    const int prepGrid = 385 + 256 + BOTH_GRID;       // transpose+prep+zero(pooled)+hist
    const int buildMmGrid = MM_G + A_G + B_G;         // mm1(enc) + expand/zbound + scatter

    hipMemsetAsync(cnt, 0, 2 * N_NODES * sizeof(int), stream);
    prep_hist_kernel<<<prepGrid, 256, 0, stream>>>(W1b, W2b, W1a, W2a, W_enc, b_enc, W0, b0,
                                                   WT, wkey, bias0, pooled, dst1, dst2, cnt, seq);
    scan1_kernel<<<SCAN1_B, 256, 0, stream>>>(cnt, cursor, partials);
    scan2_kernel<<<1, 1024, 0, stream>>>(partials);

    // ---- fused: mm1 (inline encode) || CSR build ----
    build_mm_kernel<<<buildMmGrid, 512, 0, stream>>>(x, W0, wkey, bias0, hbuf, xkey,
                                                     WuT1, WvT1, b1a, ubuf, vbuf,
                                                     src1, dst1, src2, dst2, cnt, cursor,
                                                     partials, seq, srcS, dstS, agg1, agg2);

    // ---- layer 1 edge ----
    edge_kernel<<<edgeGrid, 512, 0, stream>>>(ubuf, vbuf, xkey, srcS, dstS, WbT1,
                                              W1a + 256 * HID, agg1);

    // ---- layer 2 (mm fuses layer-1 combine; writes x1 to hbuf) ----
    mm_mfma_dual_kernel<<<MM_G, 512, 0, stream>>>(hbuf, agg1, cnt, b1b, hbuf,
                                                  WuT2, WvT2, b2a, ubuf, vbuf, N_NODES);
    edge_kernel<<<edgeGrid, 512, 0, stream>>>(ubuf, vbuf, xkey, srcS + N_EDGES, dstS + N_EDGES,
                                              WbT2, W2a + 256 * HID, agg2);

    // ---- pooling (layer-2 combine fused; pooled zeroed by prep_hist) + head ----
    pool_kernel<<<N_GRAPHS * 16, 256, 0, stream>>>(hbuf, agg2, b2b, cnt + N_NODES, batch, pooled);
    final_kernel<<<N_GRAPHS, 128, 0, stream>>>(pooled, batch, Wf1, bf1, Wf2, bf2, (float*)d_out);
}